// Round 1
// baseline (844.510 us; speedup 1.0000x reference)
//
#include <hip/hip_runtime.h>
#include <math.h>

#define B_   16
#define C_   256
#define N_   1024
#define G_   32
#define CPG  8
#define NH   4
#define HD   64
#define EPSV 1e-5f

// ---------------- Kernel 1: GroupNorm ----------------
// One block per (b, g). Each group = 8 channels x 1024 = 8192 CONTIGUOUS floats.
__global__ __launch_bounds__(256) void gn_kernel(const float* __restrict__ x,
                                                 const float* __restrict__ gw,
                                                 const float* __restrict__ gb,
                                                 float* __restrict__ xn) {
    int b = blockIdx.x / G_;
    int g = blockIdx.x % G_;
    const float4* px4 = (const float4*)(x + (size_t)(b * C_ + g * CPG) * N_);
    float4* pxn4 = (float4*)(xn + (size_t)(b * C_ + g * CPG) * N_);
    int tid = threadIdx.x;

    float s = 0.f, sq = 0.f;
    #pragma unroll
    for (int p = 0; p < 8; ++p) {
        int i = tid + p * 256;           // 2048 float4 total
        float4 v = px4[i];
        s  += v.x + v.y + v.z + v.w;
        sq += v.x * v.x + v.y * v.y + v.z * v.z + v.w * v.w;
    }
    __shared__ float red[8];
    for (int off = 32; off; off >>= 1) {
        s  += __shfl_down(s, off);
        sq += __shfl_down(sq, off);
    }
    int w = tid >> 6, lane = tid & 63;
    if (lane == 0) { red[w] = s; red[4 + w] = sq; }
    __syncthreads();
    if (tid == 0) {
        float ts = red[0] + red[1] + red[2] + red[3];
        float tq = red[4] + red[5] + red[6] + red[7];
        float mean = ts * (1.f / 8192.f);
        float var  = tq * (1.f / 8192.f) - mean * mean;
        red[0] = mean;
        red[1] = rsqrtf(var + EPSV);
    }
    __syncthreads();
    float mean = red[0], inv = red[1];
    #pragma unroll
    for (int p = 0; p < 8; ++p) {
        int i = tid + p * 256;
        int ch = g * CPG + (i >> 8);     // (i*4)/1024
        float ga = gw[ch] * inv;
        float be = gb[ch] - mean * ga;
        float4 v = px4[i];
        float4 o;
        o.x = v.x * ga + be; o.y = v.y * ga + be;
        o.z = v.z * ga + be; o.w = v.w * ga + be;
        pxn4[i] = o;
    }
}

// ---------------- Kernel 2/4: f32 tiled GEMM ----------------
// Out[b] (M x 1024) = A (M x 256, row-major) * X[b] (256 x 1024) + bias (+ resid)
// grid: (N/64, M/64, B), block 256, 4x4 micro-tile per thread.
__global__ __launch_bounds__(256) void gemm_kernel(const float* __restrict__ A,
                                                   const float* __restrict__ Xall,
                                                   const float* __restrict__ bias,
                                                   const float* __restrict__ resid,
                                                   float* __restrict__ Out, int M) {
    int b  = blockIdx.z;
    int m0 = blockIdx.y * 64, n0 = blockIdx.x * 64;
    const float* X = Xall + (size_t)b * 256 * N_;
    float* O = Out + (size_t)b * M * N_;

    __shared__ float As[32][68];   // [k][m], row stride 272B (16B-aligned)
    __shared__ float Xs[32][64];   // [k][n]

    int tid = threadIdx.x;
    int tx = tid & 15, ty = tid >> 4;
    float acc[4][4] = {};

    for (int k0 = 0; k0 < 256; k0 += 32) {
        int kk = tid & 31, mmb = tid >> 5;
        #pragma unroll
        for (int p = 0; p < 8; ++p) {
            int mm = mmb + p * 8;
            As[kk][mm] = A[(size_t)(m0 + mm) * 256 + k0 + kk];
        }
        int nn = tid & 63, kb = tid >> 6;
        #pragma unroll
        for (int p = 0; p < 8; ++p) {
            int kx = kb + p * 4;
            Xs[kx][nn] = X[(size_t)(k0 + kx) * N_ + n0 + nn];
        }
        __syncthreads();
        #pragma unroll
        for (int k = 0; k < 32; ++k) {
            float a[4], xv[4];
            #pragma unroll
            for (int i = 0; i < 4; ++i) a[i] = As[k][ty * 4 + i];
            #pragma unroll
            for (int j = 0; j < 4; ++j) xv[j] = Xs[k][tx * 4 + j];
            #pragma unroll
            for (int i = 0; i < 4; ++i)
                #pragma unroll
                for (int j = 0; j < 4; ++j) acc[i][j] += a[i] * xv[j];
        }
        __syncthreads();
    }
    #pragma unroll
    for (int i = 0; i < 4; ++i) {
        int m = m0 + ty * 4 + i;
        float bi = bias[m];
        #pragma unroll
        for (int j = 0; j < 4; ++j) {
            int n = n0 + tx * 4 + j;
            float vv = acc[i][j] + bi;
            if (resid) vv += resid[(size_t)b * M * N_ + (size_t)m * N_ + n];
            O[(size_t)m * N_ + n] = vv;
        }
    }
}

// ---------------- Kernel 3: flash attention (f32) ----------------
// qkv layout: [B][3][NH][HD][N_]. grid (N/32, NH, B), block 256 (4 waves).
// 32 queries per block, 8 per wave. Online softmax; scale folded into q.
#define QB 32
#define QW 8
__global__ __launch_bounds__(256) void attn_kernel(const float* __restrict__ qkv,
                                                   float* __restrict__ att) {
    int b = blockIdx.z, h = blockIdx.y;
    int i0 = blockIdx.x * QB;
    const float* q = qkv + ((size_t)(b * 3 + 0) * NH + h) * HD * N_;
    const float* k = qkv + ((size_t)(b * 3 + 1) * NH + h) * HD * N_;
    const float* v = qkv + ((size_t)(b * 3 + 2) * NH + h) * HD * N_;

    __shared__ float Kt[64][65];
    __shared__ float Vt[64][65];
    __shared__ float qs[QB][65];
    __shared__ float ps[QB][65];

    int tid = threadIdx.x;
    int w = tid >> 6, lane = tid & 63;

    // load q (coalesced in query index), scaled by hd^-0.5 = 0.125
    for (int idx = tid; idx < QB * 64; idx += 256) {
        int qq = idx & 31, d = idx >> 5;
        qs[qq][d] = q[(size_t)d * N_ + i0 + qq] * 0.125f;
    }

    float m[QW], l[QW], o[QW];
    #pragma unroll
    for (int i = 0; i < QW; ++i) { m[i] = -1e30f; l[i] = 0.f; o[i] = 0.f; }
    __syncthreads();

    for (int j0 = 0; j0 < N_; j0 += 64) {
        for (int idx = tid; idx < 64 * 64; idx += 256) {
            int d = idx >> 6, j = idx & 63;
            Kt[d][j] = k[(size_t)d * N_ + j0 + j];
            Vt[d][j] = v[(size_t)d * N_ + j0 + j];
        }
        __syncthreads();

        // scores: lane = key index j
        float s[QW];
        #pragma unroll
        for (int i = 0; i < QW; ++i) s[i] = 0.f;
        #pragma unroll 8
        for (int d = 0; d < 64; ++d) {
            float kv = Kt[d][lane];
            #pragma unroll
            for (int i = 0; i < QW; ++i) s[i] += qs[w * QW + i][d] * kv;
        }

        // online softmax per query
        #pragma unroll
        for (int i = 0; i < QW; ++i) {
            float tmax = s[i];
            for (int off = 32; off; off >>= 1) tmax = fmaxf(tmax, __shfl_xor(tmax, off));
            float mn = fmaxf(m[i], tmax);
            float p = __expf(s[i] - mn);
            ps[w * QW + i][lane] = p;
            float psum = p;
            for (int off = 32; off; off >>= 1) psum += __shfl_xor(psum, off);
            float alpha = __expf(m[i] - mn);
            l[i] = l[i] * alpha + psum;
            m[i] = mn;
            o[i] *= alpha;
        }

        // PV: lane = dim d
        #pragma unroll 8
        for (int j = 0; j < 64; ++j) {
            float vv = Vt[lane][j];
            #pragma unroll
            for (int i = 0; i < QW; ++i) o[i] += ps[w * QW + i][j] * vv;
        }
        __syncthreads();
    }

    // att layout: [B][C][N], channel = h*64 + d(=lane)
    float* ao = att + ((size_t)b * C_ + h * HD) * N_;
    #pragma unroll
    for (int i = 0; i < QW; ++i) {
        ao[(size_t)lane * N_ + i0 + w * QW + i] = o[i] / l[i];
    }
}

extern "C" void kernel_launch(void* const* d_in, const int* in_sizes, int n_in,
                              void* d_out, int out_size, void* d_ws, size_t ws_size,
                              hipStream_t stream) {
    const float* x      = (const float*)d_in[0];
    const float* gn_w   = (const float*)d_in[1];
    const float* gn_b   = (const float*)d_in[2];
    const float* qkv_w  = (const float*)d_in[3];
    const float* qkv_b  = (const float*)d_in[4];
    const float* proj_w = (const float*)d_in[5];
    const float* proj_b = (const float*)d_in[6];
    float* out = (float*)d_out;

    char* ws = (char*)d_ws;
    float* xn  = (float*)(ws);                          // 16 MB
    float* qkv = (float*)(ws + (size_t)16 * 1024 * 1024); // 48 MB
    float* att = xn;                                    // reuse xn region after QKV

    // 1. GroupNorm
    gn_kernel<<<dim3(B_ * G_), dim3(256), 0, stream>>>(x, gn_w, gn_b, xn);
    // 2. QKV projection: (768x256) x (256x1024) per batch
    gemm_kernel<<<dim3(16, 12, B_), dim3(256), 0, stream>>>(qkv_w, xn, qkv_b, nullptr, qkv, 768);
    // 3. Attention
    attn_kernel<<<dim3(N_ / QB, NH, B_), dim3(256), 0, stream>>>(qkv, att);
    // 4. Output projection + residual
    gemm_kernel<<<dim3(16, 4, B_), dim3(256), 0, stream>>>(proj_w, att, proj_b, x, out, 256);
}

// Round 3
// 267.393 us; speedup vs baseline: 3.1583x; 3.1583x over previous
//
#include <hip/hip_runtime.h>
#include <math.h>

#define B_   16
#define C_   256
#define N_   1024
#define G_   32
#define CPG  8
#define NH   4
#define HD   64
#define EPSV 1e-5f

typedef __attribute__((ext_vector_type(8))) short bf16x8;
typedef __attribute__((ext_vector_type(4))) float f32x4;

__device__ inline ushort f2bf(float f) {
    union { float f; unsigned u; } v; v.f = f;
    unsigned r = v.u + 0x7fffu + ((v.u >> 16) & 1u);
    return (ushort)(r >> 16);
}

// ---------------- Kernel 1: GroupNorm ----------------
__global__ __launch_bounds__(256) void gn_kernel(const float* __restrict__ x,
                                                 const float* __restrict__ gw,
                                                 const float* __restrict__ gb,
                                                 float* __restrict__ xn) {
    int b = blockIdx.x / G_;
    int g = blockIdx.x % G_;
    const float4* px4 = (const float4*)(x + (size_t)(b * C_ + g * CPG) * N_);
    float4* pxn4 = (float4*)(xn + (size_t)(b * C_ + g * CPG) * N_);
    int tid = threadIdx.x;

    float s = 0.f, sq = 0.f;
    #pragma unroll
    for (int p = 0; p < 8; ++p) {
        int i = tid + p * 256;
        float4 v = px4[i];
        s  += v.x + v.y + v.z + v.w;
        sq += v.x * v.x + v.y * v.y + v.z * v.z + v.w * v.w;
    }
    __shared__ float red[8];
    for (int off = 32; off; off >>= 1) {
        s  += __shfl_down(s, off);
        sq += __shfl_down(sq, off);
    }
    int w = tid >> 6, lane = tid & 63;
    if (lane == 0) { red[w] = s; red[4 + w] = sq; }
    __syncthreads();
    if (tid == 0) {
        float ts = red[0] + red[1] + red[2] + red[3];
        float tq = red[4] + red[5] + red[6] + red[7];
        float mean = ts * (1.f / 8192.f);
        float var  = tq * (1.f / 8192.f) - mean * mean;
        red[0] = mean;
        red[1] = rsqrtf(var + EPSV);
    }
    __syncthreads();
    float mean = red[0], inv = red[1];
    #pragma unroll
    for (int p = 0; p < 8; ++p) {
        int i = tid + p * 256;
        int ch = g * CPG + (i >> 8);
        float ga = gw[ch] * inv;
        float be = gb[ch] - mean * ga;
        float4 v = px4[i];
        float4 o;
        o.x = v.x * ga + be; o.y = v.y * ga + be;
        o.z = v.z * ga + be; o.w = v.w * ga + be;
        pxn4[i] = o;
    }
}

// ---------------- Kernel 2/4: f32 tiled GEMM ----------------
__global__ __launch_bounds__(256) void gemm_kernel(const float* __restrict__ A,
                                                   const float* __restrict__ Xall,
                                                   const float* __restrict__ bias,
                                                   const float* __restrict__ resid,
                                                   float* __restrict__ Out, int M) {
    int b  = blockIdx.z;
    int m0 = blockIdx.y * 64, n0 = blockIdx.x * 64;
    const float* X = Xall + (size_t)b * 256 * N_;
    float* O = Out + (size_t)b * M * N_;

    __shared__ float As[32][68];
    __shared__ float Xs[32][64];

    int tid = threadIdx.x;
    int tx = tid & 15, ty = tid >> 4;
    float acc[4][4] = {};

    for (int k0 = 0; k0 < 256; k0 += 32) {
        int kk = tid & 31, mmb = tid >> 5;
        #pragma unroll
        for (int p = 0; p < 8; ++p) {
            int mm = mmb + p * 8;
            As[kk][mm] = A[(size_t)(m0 + mm) * 256 + k0 + kk];
        }
        int nn = tid & 63, kb = tid >> 6;
        #pragma unroll
        for (int p = 0; p < 8; ++p) {
            int kx = kb + p * 4;
            Xs[kx][nn] = X[(size_t)(k0 + kx) * N_ + n0 + nn];
        }
        __syncthreads();
        #pragma unroll
        for (int k = 0; k < 32; ++k) {
            float a[4], xv[4];
            #pragma unroll
            for (int i = 0; i < 4; ++i) a[i] = As[k][ty * 4 + i];
            #pragma unroll
            for (int j = 0; j < 4; ++j) xv[j] = Xs[k][tx * 4 + j];
            #pragma unroll
            for (int i = 0; i < 4; ++i)
                #pragma unroll
                for (int j = 0; j < 4; ++j) acc[i][j] += a[i] * xv[j];
        }
        __syncthreads();
    }
    #pragma unroll
    for (int i = 0; i < 4; ++i) {
        int m = m0 + ty * 4 + i;
        float bi = bias[m];
        #pragma unroll
        for (int j = 0; j < 4; ++j) {
            int n = n0 + tx * 4 + j;
            float vv = acc[i][j] + bi;
            if (resid) vv += resid[(size_t)b * M * N_ + (size_t)m * N_ + n];
            O[(size_t)m * N_ + n] = vv;
        }
    }
}

// ---------------- Kernel 3: MFMA flash attention (bf16) ----------------
// qkv layout [B][3][NH][HD][N_]. grid (N_/QT=8, NH, B), block 512 (8 waves).
// Each wave owns 16 queries. KV tile = 64 keys.
#define QT 128
#define KT 64
#define NW 8

struct SmemS {
    ushort Qs[QT][72];     // [q][d]  (transposed, *0.125, bf16)
    ushort Ks[KT][72];     // [k][d]  (transposed, bf16)
    ushort Vs[KT][72];     // [d][k]  (natural, bf16)
    ushort Ps[NW][16][72]; // per-wave P tile [q][k]
};
union Smem {
    SmemS s;
    float Os[HD][QT + 4];  // output transpose staging
};

__global__ __launch_bounds__(512) void attn_mfma(const float* __restrict__ qkv,
                                                 float* __restrict__ att) {
    __shared__ Smem u;
    int b = blockIdx.z, h = blockIdx.y;
    int i0 = blockIdx.x * QT;
    const float* qp = qkv + ((size_t)(b * 3 + 0) * NH + h) * HD * N_;
    const float* kp = qkv + ((size_t)(b * 3 + 1) * NH + h) * HD * N_;
    const float* vp = qkv + ((size_t)(b * 3 + 2) * NH + h) * HD * N_;

    int tid = threadIdx.x;
    int w = tid >> 6, lane = tid & 63;
    int g = lane >> 4, r16 = lane & 15;

    // stage Q transposed: Qs[q][d] = q[d][i0+q] * 0.125
    #pragma unroll
    for (int rep = 0; rep < 4; ++rep) {
        int idx = rep * 512 + tid;      // 0..2047
        int d = idx >> 5;                // 0..63
        int qb = (idx & 31) * 4;         // 0..124
        float4 vq = *(const float4*)(qp + (size_t)d * N_ + i0 + qb);
        u.s.Qs[qb + 0][d] = f2bf(vq.x * 0.125f);
        u.s.Qs[qb + 1][d] = f2bf(vq.y * 0.125f);
        u.s.Qs[qb + 2][d] = f2bf(vq.z * 0.125f);
        u.s.Qs[qb + 3][d] = f2bf(vq.w * 0.125f);
    }

    float mrow[4], lrow[4];
    f32x4 oacc[4];
    #pragma unroll
    for (int r = 0; r < 4; ++r) { mrow[r] = -1e30f; lrow[r] = 0.f; }
    #pragma unroll
    for (int dt = 0; dt < 4; ++dt) oacc[dt] = (f32x4){0.f, 0.f, 0.f, 0.f};

    for (int j0 = 0; j0 < N_; j0 += KT) {
        __syncthreads();  // previous iter's readers done (also orders Q staging on iter 0)
        // stage K transposed: Ks[k][d]
        #pragma unroll
        for (int rep = 0; rep < 2; ++rep) {
            int idx = rep * 512 + tid;   // 0..1023
            int d = idx >> 4;             // 0..63
            int jb = (idx & 15) * 4;
            float4 vk = *(const float4*)(kp + (size_t)d * N_ + j0 + jb);
            u.s.Ks[jb + 0][d] = f2bf(vk.x);
            u.s.Ks[jb + 1][d] = f2bf(vk.y);
            u.s.Ks[jb + 2][d] = f2bf(vk.z);
            u.s.Ks[jb + 3][d] = f2bf(vk.w);
        }
        // stage V natural: Vs[d][k]
        #pragma unroll
        for (int rep = 0; rep < 2; ++rep) {
            int idx = rep * 512 + tid;
            int d = idx >> 4;
            int jb = (idx & 15) * 4;
            float4 vv = *(const float4*)(vp + (size_t)d * N_ + j0 + jb);
            ushort4 pk;
            pk.x = f2bf(vv.x); pk.y = f2bf(vv.y); pk.z = f2bf(vv.z); pk.w = f2bf(vv.w);
            *(ushort4*)&u.s.Vs[d][jb] = pk;
        }
        __syncthreads();

        // ---- QK^T: S (16 q x 64 k), A=Q-tile rows w*16.., B=K-tile ----
        f32x4 sacc[4];
        #pragma unroll
        for (int t = 0; t < 4; ++t) sacc[t] = (f32x4){0.f, 0.f, 0.f, 0.f};
        bf16x8 aQ[2];
        #pragma unroll
        for (int c = 0; c < 2; ++c)
            aQ[c] = *(const bf16x8*)((const char*)&u.s.Qs[w * 16 + r16][0] + c * 64 + g * 16);
        #pragma unroll
        for (int t = 0; t < 4; ++t) {
            #pragma unroll
            for (int c = 0; c < 2; ++c) {
                bf16x8 bK = *(const bf16x8*)((const char*)&u.s.Ks[t * 16 + r16][0] + c * 64 + g * 16);
                sacc[t] = __builtin_amdgcn_mfma_f32_16x16x32_bf16(aQ[c], bK, sacc[t], 0, 0, 0);
            }
        }

        // ---- online softmax (rows spread over 16-lane groups) ----
        #pragma unroll
        for (int r = 0; r < 4; ++r) {
            float s0 = sacc[0][r], s1 = sacc[1][r], s2 = sacc[2][r], s3 = sacc[3][r];
            float tmax = fmaxf(fmaxf(s0, s1), fmaxf(s2, s3));
            #pragma unroll
            for (int off = 8; off; off >>= 1) tmax = fmaxf(tmax, __shfl_xor(tmax, off));
            float mn = fmaxf(mrow[r], tmax);
            float p0 = __expf(s0 - mn);
            float p1 = __expf(s1 - mn);
            float p2 = __expf(s2 - mn);
            float p3 = __expf(s3 - mn);
            float psum = (p0 + p1) + (p2 + p3);
            #pragma unroll
            for (int off = 8; off; off >>= 1) psum += __shfl_xor(psum, off);
            float alpha = __expf(mrow[r] - mn);
            mrow[r] = mn;
            lrow[r] = lrow[r] * alpha + psum;
            oacc[0][r] *= alpha; oacc[1][r] *= alpha;
            oacc[2][r] *= alpha; oacc[3][r] *= alpha;
            int prow = g * 4 + r;
            u.s.Ps[w][prow][ 0 + r16] = f2bf(p0);
            u.s.Ps[w][prow][16 + r16] = f2bf(p1);
            u.s.Ps[w][prow][32 + r16] = f2bf(p2);
            u.s.Ps[w][prow][48 + r16] = f2bf(p3);
        }

        // ---- PV: O (16 q x 64 d), A=P, B=V^T ----
        bf16x8 aP[2];
        #pragma unroll
        for (int c = 0; c < 2; ++c)
            aP[c] = *(const bf16x8*)((const char*)&u.s.Ps[w][r16][0] + c * 64 + g * 16);
        #pragma unroll
        for (int dt = 0; dt < 4; ++dt) {
            #pragma unroll
            for (int c = 0; c < 2; ++c) {
                bf16x8 bV = *(const bf16x8*)((const char*)&u.s.Vs[dt * 16 + r16][0] + c * 64 + g * 16);
                oacc[dt] = __builtin_amdgcn_mfma_f32_16x16x32_bf16(aP[c], bV, oacc[dt], 0, 0, 0);
            }
        }
    }

    // ---- epilogue: normalize, transpose via LDS, coalesced store ----
    __syncthreads();   // all waves done with s.* (Os overlays the union)
    float linv[4];
    #pragma unroll
    for (int r = 0; r < 4; ++r) linv[r] = 1.f / lrow[r];
    #pragma unroll
    for (int dt = 0; dt < 4; ++dt)
        #pragma unroll
        for (int r = 0; r < 4; ++r)
            u.Os[dt * 16 + r16][w * 16 + g * 4 + r] = oacc[dt][r] * linv[r];
    __syncthreads();

    float* ao = att + ((size_t)b * C_ + h * HD) * N_ + i0;
    #pragma unroll
    for (int rep = 0; rep < 4; ++rep) {
        int idx = rep * 512 + tid;   // 0..2047
        int d = idx >> 5;             // 0..63
        int qq = (idx & 31) * 4;
        float4 o4 = *(const float4*)&u.Os[d][qq];
        *(float4*)(ao + (size_t)d * N_ + qq) = o4;
    }
}

extern "C" void kernel_launch(void* const* d_in, const int* in_sizes, int n_in,
                              void* d_out, int out_size, void* d_ws, size_t ws_size,
                              hipStream_t stream) {
    const float* x      = (const float*)d_in[0];
    const float* gn_w   = (const float*)d_in[1];
    const float* gn_b   = (const float*)d_in[2];
    const float* qkv_w  = (const float*)d_in[3];
    const float* qkv_b  = (const float*)d_in[4];
    const float* proj_w = (const float*)d_in[5];
    const float* proj_b = (const float*)d_in[6];
    float* out = (float*)d_out;

    char* ws = (char*)d_ws;
    float* xn  = (float*)(ws);                            // 16 MB
    float* qkv = (float*)(ws + (size_t)16 * 1024 * 1024); // 48 MB
    float* att = xn;                                      // reuse after QKV

    gn_kernel<<<dim3(B_ * G_), dim3(256), 0, stream>>>(x, gn_w, gn_b, xn);
    gemm_kernel<<<dim3(16, 12, B_), dim3(256), 0, stream>>>(qkv_w, xn, qkv_b, nullptr, qkv, 768);
    attn_mfma<<<dim3(N_ / QT, NH, B_), dim3(512), 0, stream>>>(qkv, att);
    gemm_kernel<<<dim3(16, 4, B_), dim3(256), 0, stream>>>(proj_w, att, proj_b, x, out, 256);
}

// Round 5
// 149.198 us; speedup vs baseline: 5.6603x; 1.7922x over previous
//
#include <hip/hip_runtime.h>
#include <math.h>

#define B_   16
#define C_   256
#define N_   1024
#define NH   4
#define HD   64
#define EPSV 1e-5f

typedef __attribute__((ext_vector_type(8))) short  bf16x8;
typedef __attribute__((ext_vector_type(8))) ushort us8;
typedef __attribute__((ext_vector_type(4))) float  f32x4;

__device__ inline ushort f2bf(float f) {
    union { float f; unsigned u; } v; v.f = f;
    unsigned r = v.u + 0x7fffu + ((v.u >> 16) & 1u);
    return (ushort)(r >> 16);
}

// ---------------- Kernel 0: weight prep (f32 -> bf16) ----------------
__global__ __launch_bounds__(256) void prep_w(const float* __restrict__ qw,
                                              const float* __restrict__ pw,
                                              ushort* __restrict__ wq,
                                              ushort* __restrict__ wp) {
    int i = blockIdx.x * 256 + threadIdx.x;
    int T = gridDim.x * 256;
    for (int t = i; t < 49152; t += T) {            // 768*256/4
        float4 v = ((const float4*)qw)[t];
        ushort4 o; o.x = f2bf(v.x); o.y = f2bf(v.y); o.z = f2bf(v.z); o.w = f2bf(v.w);
        ((ushort4*)wq)[t] = o;
    }
    for (int t = i; t < 16384; t += T) {            // 256*256/4
        float4 v = ((const float4*)pw)[t];
        ushort4 o; o.x = f2bf(v.x); o.y = f2bf(v.y); o.z = f2bf(v.z); o.w = f2bf(v.w);
        ((ushort4*)wp)[t] = o;
    }
}

// ---------------- Kernel 1: GroupNorm -> bf16 transposed [b][n][c] ----------------
// Block = (b, gp) where gp covers 16 channels (2 groups of 8). 256 threads.
__global__ __launch_bounds__(256) void gn_kernel(const float* __restrict__ x,
                                                 const float* __restrict__ gw,
                                                 const float* __restrict__ gb,
                                                 ushort* __restrict__ xnt) {
    __shared__ ushort Ls[16][1028];
    __shared__ float redS[2][4], redQ[2][4], stats[2][2];
    int b = blockIdx.x >> 4, gp = blockIdx.x & 15;
    const float4* px4 = (const float4*)(x + ((size_t)b * C_ + gp * 16) * N_);
    int tid = threadIdx.x;

    float4 vals[16];
    float s0 = 0.f, q0 = 0.f, s1 = 0.f, q1 = 0.f;
    #pragma unroll
    for (int p = 0; p < 16; ++p) {
        float4 v = px4[p * 256 + tid];
        vals[p] = v;
        float ss = v.x + v.y + v.z + v.w;
        float qq = v.x * v.x + v.y * v.y + v.z * v.z + v.w * v.w;
        if (p < 8) { s0 += ss; q0 += qq; } else { s1 += ss; q1 += qq; }
    }
    #pragma unroll
    for (int off = 32; off; off >>= 1) {
        s0 += __shfl_down(s0, off); q0 += __shfl_down(q0, off);
        s1 += __shfl_down(s1, off); q1 += __shfl_down(q1, off);
    }
    int w = tid >> 6, lane = tid & 63;
    if (lane == 0) { redS[0][w] = s0; redQ[0][w] = q0; redS[1][w] = s1; redQ[1][w] = q1; }
    __syncthreads();
    if (tid < 2) {
        float S = redS[tid][0] + redS[tid][1] + redS[tid][2] + redS[tid][3];
        float Q = redQ[tid][0] + redQ[tid][1] + redQ[tid][2] + redQ[tid][3];
        float mean = S * (1.f / 8192.f);
        float var  = Q * (1.f / 8192.f) - mean * mean;
        stats[tid][0] = mean;
        stats[tid][1] = rsqrtf(var + EPSV);
    }
    __syncthreads();
    #pragma unroll
    for (int p = 0; p < 16; ++p) {
        int grp = p >> 3;
        int ch = gp * 16 + p;
        float ga = gw[ch] * stats[grp][1];
        float be = gb[ch] - stats[grp][0] * ga;
        float4 v = vals[p];
        ushort4 o;
        o.x = f2bf(v.x * ga + be); o.y = f2bf(v.y * ga + be);
        o.z = f2bf(v.z * ga + be); o.w = f2bf(v.w * ga + be);
        *(ushort4*)&Ls[p][tid * 4] = o;
    }
    __syncthreads();
    #pragma unroll
    for (int it = 0; it < 4; ++it) {
        int n = it * 256 + tid;
        us8 a, b2;
        #pragma unroll
        for (int c = 0; c < 8; ++c) { a[c] = Ls[c][n]; b2[c] = Ls[8 + c][n]; }
        ushort* dst = xnt + ((size_t)b * N_ + n) * C_ + gp * 16;
        *(us8*)dst = a;
        *(us8*)(dst + 8) = b2;
    }
}

// ---------------- Kernel 2: QKV GEMM (bf16 MFMA) ----------------
// M=768 (mt: s*4+h, 64 d each), N=1024, K=256. Tile 64x128, 4 waves (2m x 2n).
// Q/K out: [b][h][n][d] bf16 (LDS transpose). V out: [b][h][d][n] bf16.
__global__ __launch_bounds__(256) void qkv_gemm(const ushort* __restrict__ wq,
                                                const ushort* __restrict__ xnt,
                                                const float* __restrict__ bias,
                                                ushort* __restrict__ Qd,
                                                ushort* __restrict__ Kd,
                                                ushort* __restrict__ Vd) {
    __shared__ union {
        struct { ushort As[64][72]; ushort Bs[128][72]; } s;
        ushort Ts[128][72];
    } u;
    int b = blockIdx.z, mt = blockIdx.y, n0 = blockIdx.x * 128;
    int s_ = mt >> 2, h = mt & 3;
    const ushort* Bsrc = xnt + (size_t)b * N_ * C_;
    int tid = threadIdx.x;
    int w = tid >> 6, lane = tid & 63;
    int g = lane >> 4, r16 = lane & 15;
    int wm = w >> 1, wn = w & 1;

    f32x4 acc[2][4];
    #pragma unroll
    for (int mf = 0; mf < 2; ++mf)
        #pragma unroll
        for (int nf = 0; nf < 4; ++nf) acc[mf][nf] = (f32x4){0.f, 0.f, 0.f, 0.f};

    for (int k0 = 0; k0 < 256; k0 += 64) {
        __syncthreads();
        #pragma unroll
        for (int it = 0; it < 2; ++it) {
            int t = it * 256 + tid, r = t >> 3, c = t & 7;
            *(us8*)&u.s.As[r][c * 8] = *(const us8*)(wq + (size_t)(mt * 64 + r) * 256 + k0 + c * 8);
        }
        #pragma unroll
        for (int it = 0; it < 4; ++it) {
            int t = it * 256 + tid, r = t >> 3, c = t & 7;
            *(us8*)&u.s.Bs[r][c * 8] = *(const us8*)(Bsrc + (size_t)(n0 + r) * 256 + k0 + c * 8);
        }
        __syncthreads();
        bf16x8 aA[2][2], bB[4][2];
        #pragma unroll
        for (int mf = 0; mf < 2; ++mf)
            #pragma unroll
            for (int ks = 0; ks < 2; ++ks)
                aA[mf][ks] = *(const bf16x8*)&u.s.As[wm * 32 + mf * 16 + r16][ks * 32 + g * 8];
        #pragma unroll
        for (int nf = 0; nf < 4; ++nf)
            #pragma unroll
            for (int ks = 0; ks < 2; ++ks)
                bB[nf][ks] = *(const bf16x8*)&u.s.Bs[wn * 64 + nf * 16 + r16][ks * 32 + g * 8];
        #pragma unroll
        for (int ks = 0; ks < 2; ++ks)
            #pragma unroll
            for (int mf = 0; mf < 2; ++mf)
                #pragma unroll
                for (int nf = 0; nf < 4; ++nf)
                    acc[mf][nf] = __builtin_amdgcn_mfma_f32_16x16x32_bf16(aA[mf][ks], bB[nf][ks], acc[mf][nf], 0, 0, 0);
    }
    __syncthreads();

    float scale = (s_ == 0) ? 0.125f : 1.f;
    float bfr[2][4];
    #pragma unroll
    for (int mf = 0; mf < 2; ++mf)
        #pragma unroll
        for (int reg = 0; reg < 4; ++reg)
            bfr[mf][reg] = bias[mt * 64 + wm * 32 + mf * 16 + g * 4 + reg];

    if (s_ < 2) {
        #pragma unroll
        for (int mf = 0; mf < 2; ++mf)
            #pragma unroll
            for (int nf = 0; nf < 4; ++nf)
                #pragma unroll
                for (int reg = 0; reg < 4; ++reg)
                    u.Ts[wn * 64 + nf * 16 + r16][wm * 32 + mf * 16 + g * 4 + reg] =
                        f2bf((acc[mf][nf][reg] + bfr[mf][reg]) * scale);
        __syncthreads();
        ushort* dst = (s_ == 0 ? Qd : Kd) + ((size_t)(b * NH + h) * N_ + n0) * HD;
        #pragma unroll
        for (int it = 0; it < 4; ++it) {
            int t = it * 256 + tid, r = t >> 3, c = t & 7;
            *(us8*)(dst + (size_t)r * HD + c * 8) = *(const us8*)&u.Ts[r][c * 8];
        }
    } else {
        #pragma unroll
        for (int mf = 0; mf < 2; ++mf)
            #pragma unroll
            for (int nf = 0; nf < 4; ++nf)
                #pragma unroll
                for (int reg = 0; reg < 4; ++reg) {
                    int d = wm * 32 + mf * 16 + g * 4 + reg;
                    int n = n0 + wn * 64 + nf * 16 + r16;
                    Vd[((size_t)(b * NH + h) * HD + d) * N_ + n] = f2bf(acc[mf][nf][reg] + bfr[mf][reg]);
                }
    }
}

// ---------------- Kernel 3: MFMA flash attention (pure bf16 staging) ----------------
#define QT 128
#define KT 64
__global__ __launch_bounds__(512) void attn_mfma(const ushort* __restrict__ Qd,
                                                 const ushort* __restrict__ Kd,
                                                 const ushort* __restrict__ Vd,
                                                 ushort* __restrict__ att) {
    __shared__ union {
        struct { ushort Ks[64][72]; ushort Vs[64][72]; ushort Ps[8][16][72]; } s;
        float Op[128][68];
    } u;
    int b = blockIdx.z, h = blockIdx.y;
    int i0 = blockIdx.x * QT;
    int bh = b * NH + h;
    const ushort* qp = Qd + (size_t)bh * N_ * HD;
    const ushort* kp = Kd + (size_t)bh * N_ * HD;
    const ushort* vp = Vd + (size_t)bh * HD * N_;

    int tid = threadIdx.x;
    int w = tid >> 6, lane = tid & 63;
    int g = lane >> 4, r16 = lane & 15;
    int sr = tid >> 3, sc = tid & 7;      // staging row/chunk

    // Q fragments straight from global (row = query, 8 contiguous d per lane)
    bf16x8 aQ[2];
    #pragma unroll
    for (int c = 0; c < 2; ++c)
        aQ[c] = *(const bf16x8*)(qp + (size_t)(i0 + w * 16 + r16) * HD + c * 32 + g * 8);

    float mrow[4], lrow[4];
    f32x4 oacc[4];
    #pragma unroll
    for (int r = 0; r < 4; ++r) { mrow[r] = -1e30f; lrow[r] = 0.f; }
    #pragma unroll
    for (int dt = 0; dt < 4; ++dt) oacc[dt] = (f32x4){0.f, 0.f, 0.f, 0.f};

    for (int j0 = 0; j0 < N_; j0 += KT) {
        __syncthreads();
        // 512 threads = 512 16B-chunks per tile: conflict-free (36r+4c) pattern
        *(us8*)&u.s.Ks[sr][sc * 8] = *(const us8*)(kp + (size_t)(j0 + sr) * HD + sc * 8);
        *(us8*)&u.s.Vs[sr][sc * 8] = *(const us8*)(vp + (size_t)sr * N_ + j0 + sc * 8);
        __syncthreads();

        // ---- QK^T ----
        f32x4 sacc[4];
        #pragma unroll
        for (int t = 0; t < 4; ++t) sacc[t] = (f32x4){0.f, 0.f, 0.f, 0.f};
        #pragma unroll
        for (int t = 0; t < 4; ++t)
            #pragma unroll
            for (int c = 0; c < 2; ++c) {
                bf16x8 bK = *(const bf16x8*)&u.s.Ks[t * 16 + r16][c * 32 + g * 8];
                sacc[t] = __builtin_amdgcn_mfma_f32_16x16x32_bf16(aQ[c], bK, sacc[t], 0, 0, 0);
            }

        // ---- online softmax ----
        #pragma unroll
        for (int r = 0; r < 4; ++r) {
            float s0 = sacc[0][r], s1 = sacc[1][r], s2 = sacc[2][r], s3 = sacc[3][r];
            float tmax = fmaxf(fmaxf(s0, s1), fmaxf(s2, s3));
            #pragma unroll
            for (int off = 8; off; off >>= 1) tmax = fmaxf(tmax, __shfl_xor(tmax, off));
            float mn = fmaxf(mrow[r], tmax);
            float p0 = __expf(s0 - mn);
            float p1 = __expf(s1 - mn);
            float p2 = __expf(s2 - mn);
            float p3 = __expf(s3 - mn);
            float psum = (p0 + p1) + (p2 + p3);
            #pragma unroll
            for (int off = 8; off; off >>= 1) psum += __shfl_xor(psum, off);
            float alpha = __expf(mrow[r] - mn);
            mrow[r] = mn;
            lrow[r] = lrow[r] * alpha + psum;
            oacc[0][r] *= alpha; oacc[1][r] *= alpha;
            oacc[2][r] *= alpha; oacc[3][r] *= alpha;
            int prow = g * 4 + r;
            u.s.Ps[w][prow][ 0 + r16] = f2bf(p0);
            u.s.Ps[w][prow][16 + r16] = f2bf(p1);
            u.s.Ps[w][prow][32 + r16] = f2bf(p2);
            u.s.Ps[w][prow][48 + r16] = f2bf(p3);
        }

        // ---- PV ----
        bf16x8 aP[2];
        #pragma unroll
        for (int c = 0; c < 2; ++c)
            aP[c] = *(const bf16x8*)&u.s.Ps[w][r16][c * 32 + g * 8];
        #pragma unroll
        for (int dt = 0; dt < 4; ++dt)
            #pragma unroll
            for (int c = 0; c < 2; ++c) {
                bf16x8 bV = *(const bf16x8*)&u.s.Vs[dt * 16 + r16][c * 32 + g * 8];
                oacc[dt] = __builtin_amdgcn_mfma_f32_16x16x32_bf16(aP[c], bV, oacc[dt], 0, 0, 0);
            }
    }

    // ---- epilogue: att_t[b][n][h*64+d] bf16 ----
    __syncthreads();
    float linv[4];
    #pragma unroll
    for (int r = 0; r < 4; ++r) linv[r] = 1.f / lrow[r];
    #pragma unroll
    for (int dt = 0; dt < 4; ++dt)
        #pragma unroll
        for (int r = 0; r < 4; ++r)
            u.Op[w * 16 + g * 4 + r][dt * 16 + r16] = oacc[dt][r] * linv[r];
    __syncthreads();

    #pragma unroll
    for (int it = 0; it < 2; ++it) {
        int t = it * 512 + tid;
        int r = t >> 3, c = t & 7;          // 128 q-rows x 8 chunks of 8 d
        f32x4 v0 = *(const f32x4*)&u.Op[r][c * 8];
        f32x4 v1 = *(const f32x4*)&u.Op[r][c * 8 + 4];
        us8 o;
        o[0] = f2bf(v0[0]); o[1] = f2bf(v0[1]); o[2] = f2bf(v0[2]); o[3] = f2bf(v0[3]);
        o[4] = f2bf(v1[0]); o[5] = f2bf(v1[1]); o[6] = f2bf(v1[2]); o[7] = f2bf(v1[3]);
        *(us8*)(att + ((size_t)b * N_ + i0 + r) * C_ + h * HD + c * 8) = o;
    }
}

// ---------------- Kernel 4: proj GEMM (bf16 MFMA) + bias + residual ----------------
__global__ __launch_bounds__(256) void proj_gemm(const ushort* __restrict__ wp,
                                                 const ushort* __restrict__ att,
                                                 const float* __restrict__ bias,
                                                 const float* __restrict__ x,
                                                 float* __restrict__ out) {
    __shared__ struct { ushort As[64][72]; ushort Bs[128][72]; } s;
    int b = blockIdx.z, m0 = blockIdx.y * 64, n0 = blockIdx.x * 128;
    const ushort* Bsrc = att + (size_t)b * N_ * C_;
    int tid = threadIdx.x;
    int w = tid >> 6, lane = tid & 63;
    int g = lane >> 4, r16 = lane & 15;
    int wm = w >> 1, wn = w & 1;

    f32x4 acc[2][4];
    #pragma unroll
    for (int mf = 0; mf < 2; ++mf)
        #pragma unroll
        for (int nf = 0; nf < 4; ++nf) acc[mf][nf] = (f32x4){0.f, 0.f, 0.f, 0.f};

    for (int k0 = 0; k0 < 256; k0 += 64) {
        __syncthreads();
        #pragma unroll
        for (int it = 0; it < 2; ++it) {
            int t = it * 256 + tid, r = t >> 3, c = t & 7;
            *(us8*)&s.As[r][c * 8] = *(const us8*)(wp + (size_t)(m0 + r) * 256 + k0 + c * 8);
        }
        #pragma unroll
        for (int it = 0; it < 4; ++it) {
            int t = it * 256 + tid, r = t >> 3, c = t & 7;
            *(us8*)&s.Bs[r][c * 8] = *(const us8*)(Bsrc + (size_t)(n0 + r) * 256 + k0 + c * 8);
        }
        __syncthreads();
        bf16x8 aA[2][2], bB[4][2];
        #pragma unroll
        for (int mf = 0; mf < 2; ++mf)
            #pragma unroll
            for (int ks = 0; ks < 2; ++ks)
                aA[mf][ks] = *(const bf16x8*)&s.As[wm * 32 + mf * 16 + r16][ks * 32 + g * 8];
        #pragma unroll
        for (int nf = 0; nf < 4; ++nf)
            #pragma unroll
            for (int ks = 0; ks < 2; ++ks)
                bB[nf][ks] = *(const bf16x8*)&s.Bs[wn * 64 + nf * 16 + r16][ks * 32 + g * 8];
        #pragma unroll
        for (int ks = 0; ks < 2; ++ks)
            #pragma unroll
            for (int mf = 0; mf < 2; ++mf)
                #pragma unroll
                for (int nf = 0; nf < 4; ++nf)
                    acc[mf][nf] = __builtin_amdgcn_mfma_f32_16x16x32_bf16(aA[mf][ks], bB[nf][ks], acc[mf][nf], 0, 0, 0);
    }

    #pragma unroll
    for (int mf = 0; mf < 2; ++mf) {
        #pragma unroll
        for (int reg = 0; reg < 4; ++reg) {
            int c_ = m0 + wm * 32 + mf * 16 + g * 4 + reg;
            float bi = bias[c_];
            #pragma unroll
            for (int nf = 0; nf < 4; ++nf) {
                int n = n0 + wn * 64 + nf * 16 + r16;
                size_t o = ((size_t)b * C_ + c_) * N_ + n;
                out[o] = acc[mf][nf][reg] + bi + x[o];
            }
        }
    }
}

extern "C" void kernel_launch(void* const* d_in, const int* in_sizes, int n_in,
                              void* d_out, int out_size, void* d_ws, size_t ws_size,
                              hipStream_t stream) {
    const float* x      = (const float*)d_in[0];
    const float* gn_w   = (const float*)d_in[1];
    const float* gn_b   = (const float*)d_in[2];
    const float* qkv_w  = (const float*)d_in[3];
    const float* qkv_b  = (const float*)d_in[4];
    const float* proj_w = (const float*)d_in[5];
    const float* proj_b = (const float*)d_in[6];
    float* out = (float*)d_out;

    char* ws = (char*)d_ws;
    ushort* wq_bf = (ushort*)(ws);                               // 384 KB
    ushort* wp_bf = (ushort*)(ws + 393216);                      // 128 KB
    ushort* xnt   = (ushort*)(ws + (1u << 20));                  // 8 MB  [b][n][c]
    ushort* Qd    = (ushort*)(ws + (size_t)16 * 1024 * 1024);    // 8 MB  [b][h][n][d]
    ushort* Kd    = (ushort*)(ws + (size_t)24 * 1024 * 1024);    // 8 MB  [b][h][n][d]
    ushort* Vd    = (ushort*)(ws + (size_t)32 * 1024 * 1024);    // 8 MB  [b][h][d][n]
    ushort* att_t = (ushort*)(ws + (size_t)40 * 1024 * 1024);    // 8 MB  [b][n][c]

    prep_w<<<dim3(256), dim3(256), 0, stream>>>(qkv_w, proj_w, wq_bf, wp_bf);
    gn_kernel<<<dim3(B_ * 16), dim3(256), 0, stream>>>(x, gn_w, gn_b, xnt);
    qkv_gemm<<<dim3(8, 12, B_), dim3(256), 0, stream>>>(wq_bf, xnt, qkv_b, Qd, Kd, Vd);
    attn_mfma<<<dim3(N_ / QT, NH, B_), dim3(512), 0, stream>>>(Qd, Kd, Vd, att_t);
    proj_gemm<<<dim3(8, 4, B_), dim3(256), 0, stream>>>(wp_bf, att_t, proj_b, x, out);
}

// Round 6
// 122.598 us; speedup vs baseline: 6.8885x; 1.2170x over previous
//
#include <hip/hip_runtime.h>
#include <math.h>

#define B_   16
#define C_   256
#define N_   1024
#define NH   4
#define HD   64
#define EPSV 1e-5f

typedef __attribute__((ext_vector_type(8))) short  bf16x8;
typedef __attribute__((ext_vector_type(8))) ushort us8;
typedef __attribute__((ext_vector_type(4))) float  f32x4;

__device__ inline ushort f2bf(float f) {
    union { float f; unsigned u; } v; v.f = f;
    unsigned r = v.u + 0x7fffu + ((v.u >> 16) & 1u);
    return (ushort)(r >> 16);
}

// ---------------- Kernel 0: weight prep (f32 -> bf16) ----------------
__global__ __launch_bounds__(256) void prep_w(const float* __restrict__ qw,
                                              const float* __restrict__ pw,
                                              ushort* __restrict__ wq,
                                              ushort* __restrict__ wp) {
    int i = blockIdx.x * 256 + threadIdx.x;
    int T = gridDim.x * 256;
    for (int t = i; t < 49152; t += T) {
        float4 v = ((const float4*)qw)[t];
        ushort4 o; o.x = f2bf(v.x); o.y = f2bf(v.y); o.z = f2bf(v.z); o.w = f2bf(v.w);
        ((ushort4*)wq)[t] = o;
    }
    for (int t = i; t < 16384; t += T) {
        float4 v = ((const float4*)pw)[t];
        ushort4 o; o.x = f2bf(v.x); o.y = f2bf(v.y); o.z = f2bf(v.z); o.w = f2bf(v.w);
        ((ushort4*)wp)[t] = o;
    }
}

// ---------------- Kernel 1: GroupNorm -> bf16 transposed [b][n][c] ----------------
__global__ __launch_bounds__(256) void gn_kernel(const float* __restrict__ x,
                                                 const float* __restrict__ gw,
                                                 const float* __restrict__ gb,
                                                 ushort* __restrict__ xnt) {
    __shared__ ushort Ls[16][1028];
    __shared__ float redS[2][4], redQ[2][4], stats[2][2];
    int b = blockIdx.x >> 4, gp = blockIdx.x & 15;
    const float4* px4 = (const float4*)(x + ((size_t)b * C_ + gp * 16) * N_);
    int tid = threadIdx.x;

    float4 vals[16];
    float s0 = 0.f, q0 = 0.f, s1 = 0.f, q1 = 0.f;
    #pragma unroll
    for (int p = 0; p < 16; ++p) {
        float4 v = px4[p * 256 + tid];
        vals[p] = v;
        float ss = v.x + v.y + v.z + v.w;
        float qq = v.x * v.x + v.y * v.y + v.z * v.z + v.w * v.w;
        if (p < 8) { s0 += ss; q0 += qq; } else { s1 += ss; q1 += qq; }
    }
    #pragma unroll
    for (int off = 32; off; off >>= 1) {
        s0 += __shfl_down(s0, off); q0 += __shfl_down(q0, off);
        s1 += __shfl_down(s1, off); q1 += __shfl_down(q1, off);
    }
    int w = tid >> 6, lane = tid & 63;
    if (lane == 0) { redS[0][w] = s0; redQ[0][w] = q0; redS[1][w] = s1; redQ[1][w] = q1; }
    __syncthreads();
    if (tid < 2) {
        float S = redS[tid][0] + redS[tid][1] + redS[tid][2] + redS[tid][3];
        float Q = redQ[tid][0] + redQ[tid][1] + redQ[tid][2] + redQ[tid][3];
        float mean = S * (1.f / 8192.f);
        float var  = Q * (1.f / 8192.f) - mean * mean;
        stats[tid][0] = mean;
        stats[tid][1] = rsqrtf(var + EPSV);
    }
    __syncthreads();
    #pragma unroll
    for (int p = 0; p < 16; ++p) {
        int grp = p >> 3;
        int ch = gp * 16 + p;
        float ga = gw[ch] * stats[grp][1];
        float be = gb[ch] - stats[grp][0] * ga;
        float4 v = vals[p];
        ushort4 o;
        o.x = f2bf(v.x * ga + be); o.y = f2bf(v.y * ga + be);
        o.z = f2bf(v.z * ga + be); o.w = f2bf(v.w * ga + be);
        *(ushort4*)&Ls[p][tid * 4] = o;
    }
    __syncthreads();
    #pragma unroll
    for (int it = 0; it < 4; ++it) {
        int n = it * 256 + tid;
        us8 a, b2;
        #pragma unroll
        for (int c = 0; c < 8; ++c) { a[c] = Ls[c][n]; b2[c] = Ls[8 + c][n]; }
        ushort* dst = xnt + ((size_t)b * N_ + n) * C_ + gp * 16;
        *(us8*)dst = a;
        *(us8*)(dst + 8) = b2;
    }
}

// ---------------- Kernel 2: QKV GEMM (bf16 MFMA) ----------------
__global__ __launch_bounds__(256) void qkv_gemm(const ushort* __restrict__ wq,
                                                const ushort* __restrict__ xnt,
                                                const float* __restrict__ bias,
                                                ushort* __restrict__ Qd,
                                                ushort* __restrict__ Kd,
                                                ushort* __restrict__ Vd) {
    __shared__ union {
        struct { ushort As[64][72]; ushort Bs[128][72]; } s;
        ushort Ts[128][72];
    } u;
    int b = blockIdx.z, mt = blockIdx.y, n0 = blockIdx.x * 128;
    int s_ = mt >> 2, h = mt & 3;
    const ushort* Bsrc = xnt + (size_t)b * N_ * C_;
    int tid = threadIdx.x;
    int w = tid >> 6, lane = tid & 63;
    int g = lane >> 4, r16 = lane & 15;
    int wm = w >> 1, wn = w & 1;

    f32x4 acc[2][4];
    #pragma unroll
    for (int mf = 0; mf < 2; ++mf)
        #pragma unroll
        for (int nf = 0; nf < 4; ++nf) acc[mf][nf] = (f32x4){0.f, 0.f, 0.f, 0.f};

    for (int k0 = 0; k0 < 256; k0 += 64) {
        __syncthreads();
        #pragma unroll
        for (int it = 0; it < 2; ++it) {
            int t = it * 256 + tid, r = t >> 3, c = t & 7;
            *(us8*)&u.s.As[r][c * 8] = *(const us8*)(wq + (size_t)(mt * 64 + r) * 256 + k0 + c * 8);
        }
        #pragma unroll
        for (int it = 0; it < 4; ++it) {
            int t = it * 256 + tid, r = t >> 3, c = t & 7;
            *(us8*)&u.s.Bs[r][c * 8] = *(const us8*)(Bsrc + (size_t)(n0 + r) * 256 + k0 + c * 8);
        }
        __syncthreads();
        bf16x8 aA[2][2], bB[4][2];
        #pragma unroll
        for (int mf = 0; mf < 2; ++mf)
            #pragma unroll
            for (int ks = 0; ks < 2; ++ks)
                aA[mf][ks] = *(const bf16x8*)&u.s.As[wm * 32 + mf * 16 + r16][ks * 32 + g * 8];
        #pragma unroll
        for (int nf = 0; nf < 4; ++nf)
            #pragma unroll
            for (int ks = 0; ks < 2; ++ks)
                bB[nf][ks] = *(const bf16x8*)&u.s.Bs[wn * 64 + nf * 16 + r16][ks * 32 + g * 8];
        #pragma unroll
        for (int ks = 0; ks < 2; ++ks)
            #pragma unroll
            for (int mf = 0; mf < 2; ++mf)
                #pragma unroll
                for (int nf = 0; nf < 4; ++nf)
                    acc[mf][nf] = __builtin_amdgcn_mfma_f32_16x16x32_bf16(aA[mf][ks], bB[nf][ks], acc[mf][nf], 0, 0, 0);
    }
    __syncthreads();

    float scale = (s_ == 0) ? 0.125f : 1.f;
    float bfr[2][4];
    #pragma unroll
    for (int mf = 0; mf < 2; ++mf)
        #pragma unroll
        for (int reg = 0; reg < 4; ++reg)
            bfr[mf][reg] = bias[mt * 64 + wm * 32 + mf * 16 + g * 4 + reg];

    if (s_ < 2) {
        #pragma unroll
        for (int mf = 0; mf < 2; ++mf)
            #pragma unroll
            for (int nf = 0; nf < 4; ++nf)
                #pragma unroll
                for (int reg = 0; reg < 4; ++reg)
                    u.Ts[wn * 64 + nf * 16 + r16][wm * 32 + mf * 16 + g * 4 + reg] =
                        f2bf((acc[mf][nf][reg] + bfr[mf][reg]) * scale);
        __syncthreads();
        ushort* dst = (s_ == 0 ? Qd : Kd) + ((size_t)(b * NH + h) * N_ + n0) * HD;
        #pragma unroll
        for (int it = 0; it < 4; ++it) {
            int t = it * 256 + tid, r = t >> 3, c = t & 7;
            *(us8*)(dst + (size_t)r * HD + c * 8) = *(const us8*)&u.Ts[r][c * 8];
        }
    } else {
        #pragma unroll
        for (int mf = 0; mf < 2; ++mf)
            #pragma unroll
            for (int nf = 0; nf < 4; ++nf)
                #pragma unroll
                for (int reg = 0; reg < 4; ++reg) {
                    int d = wm * 32 + mf * 16 + g * 4 + reg;
                    int n = n0 + wn * 64 + nf * 16 + r16;
                    Vd[((size_t)(b * NH + h) * HD + d) * N_ + n] = f2bf(acc[mf][nf][reg] + bfr[mf][reg]);
                }
    }
}

// ---------------- Kernel 3: MFMA flash attention v3 ----------------
// 1D grid 512: bh = n&63 (XCD-local K/V), qt = n>>6. 256 threads, 4 waves x 32 q.
// Double-buffered K/V LDS, async-stage split, 1 barrier/iter.
#define QT 128
#define KT 64
__global__ __launch_bounds__(256) void attn_mfma(const ushort* __restrict__ Qd,
                                                 const ushort* __restrict__ Kd,
                                                 const ushort* __restrict__ Vd,
                                                 ushort* __restrict__ att) {
    __shared__ union {
        struct {
            ushort Kb[2][64][72];
            ushort Vb[2][64][72];
            ushort Ps[4][32][72];
        } s;
        float Op[128][68];
    } u;
    int nblk = blockIdx.x;
    int bh = nblk & 63, qt = nblk >> 6;
    int b = bh >> 2, h = bh & 3;
    int i0 = qt * QT;
    const ushort* qp = Qd + (size_t)bh * N_ * HD;
    const ushort* kp = Kd + (size_t)bh * N_ * HD;
    const ushort* vp = Vd + (size_t)bh * HD * N_;

    int tid = threadIdx.x;
    int w = tid >> 6, lane = tid & 63;
    int g = lane >> 4, r16 = lane & 15;
    int sr = tid >> 3, sc = tid & 7;     // staging: rows sr, sr+32; chunk sc

    // Q fragments (2 x 16-row frags per wave = 32 queries), from global
    bf16x8 aQ[2][2];
    #pragma unroll
    for (int qf = 0; qf < 2; ++qf)
        #pragma unroll
        for (int c = 0; c < 2; ++c)
            aQ[qf][c] = *(const bf16x8*)(qp + (size_t)(i0 + w * 32 + qf * 16 + r16) * HD + c * 32 + g * 8);

    float mrow[2][4], lrow[2][4];
    f32x4 oacc[2][4];
    #pragma unroll
    for (int qf = 0; qf < 2; ++qf) {
        #pragma unroll
        for (int r = 0; r < 4; ++r) { mrow[qf][r] = -1e30f; lrow[qf][r] = 0.f; }
        #pragma unroll
        for (int dt = 0; dt < 4; ++dt) oacc[qf][dt] = (f32x4){0.f, 0.f, 0.f, 0.f};
    }

    // prologue: stage tile 0 into buffer 0
    {
        us8 ka = *(const us8*)(kp + (size_t)sr * HD + sc * 8);
        us8 kb = *(const us8*)(kp + (size_t)(sr + 32) * HD + sc * 8);
        us8 va = *(const us8*)(vp + (size_t)sr * N_ + sc * 8);
        us8 vb = *(const us8*)(vp + (size_t)(sr + 32) * N_ + sc * 8);
        *(us8*)&u.s.Kb[0][sr][sc * 8] = ka;
        *(us8*)&u.s.Kb[0][sr + 32][sc * 8] = kb;
        *(us8*)&u.s.Vb[0][sr][sc * 8] = va;
        *(us8*)&u.s.Vb[0][sr + 32][sc * 8] = vb;
    }

    for (int it = 0; it < 16; ++it) {
        int cur = it & 1;
        // issue next tile's global loads early (T14): latency hides under compute
        us8 ka, kb, va, vb;
        if (it < 15) {
            int j0n = (it + 1) * KT;
            ka = *(const us8*)(kp + (size_t)(j0n + sr) * HD + sc * 8);
            kb = *(const us8*)(kp + (size_t)(j0n + sr + 32) * HD + sc * 8);
            va = *(const us8*)(vp + (size_t)sr * N_ + j0n + sc * 8);
            vb = *(const us8*)(vp + (size_t)(sr + 32) * N_ + j0n + sc * 8);
        }
        __syncthreads();   // buf[cur] staged & visible; buf[cur^1] readers (iter it-1) done

        // ---- QK^T: 2 q-frags x 64 keys ----
        f32x4 sacc[2][4];
        #pragma unroll
        for (int qf = 0; qf < 2; ++qf)
            #pragma unroll
            for (int t = 0; t < 4; ++t) sacc[qf][t] = (f32x4){0.f, 0.f, 0.f, 0.f};
        __builtin_amdgcn_s_setprio(1);
        #pragma unroll
        for (int t = 0; t < 4; ++t)
            #pragma unroll
            for (int c = 0; c < 2; ++c) {
                bf16x8 bK = *(const bf16x8*)&u.s.Kb[cur][t * 16 + r16][c * 32 + g * 8];
                #pragma unroll
                for (int qf = 0; qf < 2; ++qf)
                    sacc[qf][t] = __builtin_amdgcn_mfma_f32_16x16x32_bf16(aQ[qf][c], bK, sacc[qf][t], 0, 0, 0);
            }
        __builtin_amdgcn_s_setprio(0);

        // ---- online softmax ----
        #pragma unroll
        for (int qf = 0; qf < 2; ++qf)
            #pragma unroll
            for (int r = 0; r < 4; ++r) {
                float s0 = sacc[qf][0][r], s1 = sacc[qf][1][r], s2 = sacc[qf][2][r], s3 = sacc[qf][3][r];
                float tmax = fmaxf(fmaxf(s0, s1), fmaxf(s2, s3));
                #pragma unroll
                for (int off = 8; off; off >>= 1) tmax = fmaxf(tmax, __shfl_xor(tmax, off));
                float mn = fmaxf(mrow[qf][r], tmax);
                float p0 = __expf(s0 - mn);
                float p1 = __expf(s1 - mn);
                float p2 = __expf(s2 - mn);
                float p3 = __expf(s3 - mn);
                float psum = (p0 + p1) + (p2 + p3);
                #pragma unroll
                for (int off = 8; off; off >>= 1) psum += __shfl_xor(psum, off);
                float alpha = __expf(mrow[qf][r] - mn);
                mrow[qf][r] = mn;
                lrow[qf][r] = lrow[qf][r] * alpha + psum;
                oacc[qf][0][r] *= alpha; oacc[qf][1][r] *= alpha;
                oacc[qf][2][r] *= alpha; oacc[qf][3][r] *= alpha;
                int prow = qf * 16 + g * 4 + r;
                u.s.Ps[w][prow][ 0 + r16] = f2bf(p0);
                u.s.Ps[w][prow][16 + r16] = f2bf(p1);
                u.s.Ps[w][prow][32 + r16] = f2bf(p2);
                u.s.Ps[w][prow][48 + r16] = f2bf(p3);
            }

        // ---- PV: bV fragments shared across both q-frags ----
        bf16x8 aP[2][2];
        #pragma unroll
        for (int qf = 0; qf < 2; ++qf)
            #pragma unroll
            for (int c = 0; c < 2; ++c)
                aP[qf][c] = *(const bf16x8*)&u.s.Ps[w][qf * 16 + r16][c * 32 + g * 8];
        __builtin_amdgcn_s_setprio(1);
        #pragma unroll
        for (int dt = 0; dt < 4; ++dt)
            #pragma unroll
            for (int c = 0; c < 2; ++c) {
                bf16x8 bV = *(const bf16x8*)&u.s.Vb[cur][dt * 16 + r16][c * 32 + g * 8];
                #pragma unroll
                for (int qf = 0; qf < 2; ++qf)
                    oacc[qf][dt] = __builtin_amdgcn_mfma_f32_16x16x32_bf16(aP[qf][c], bV, oacc[qf][dt], 0, 0, 0);
            }
        __builtin_amdgcn_s_setprio(0);

        // write prefetched tile into the other buffer (readers finished at top barrier)
        if (it < 15) {
            *(us8*)&u.s.Kb[cur ^ 1][sr][sc * 8] = ka;
            *(us8*)&u.s.Kb[cur ^ 1][sr + 32][sc * 8] = kb;
            *(us8*)&u.s.Vb[cur ^ 1][sr][sc * 8] = va;
            *(us8*)&u.s.Vb[cur ^ 1][sr + 32][sc * 8] = vb;
        }
    }

    // ---- epilogue: normalize, transpose via LDS, bf16 [b][n][c] store ----
    __syncthreads();
    #pragma unroll
    for (int qf = 0; qf < 2; ++qf) {
        float linv[4];
        #pragma unroll
        for (int r = 0; r < 4; ++r) linv[r] = 1.f / lrow[qf][r];
        #pragma unroll
        for (int dt = 0; dt < 4; ++dt)
            #pragma unroll
            for (int r = 0; r < 4; ++r)
                u.Op[w * 32 + qf * 16 + g * 4 + r][dt * 16 + r16] = oacc[qf][dt][r] * linv[r];
    }
    __syncthreads();

    #pragma unroll
    for (int it = 0; it < 4; ++it) {
        int t = it * 256 + tid;
        int r = t >> 3, c = t & 7;
        f32x4 v0 = *(const f32x4*)&u.Op[r][c * 8];
        f32x4 v1 = *(const f32x4*)&u.Op[r][c * 8 + 4];
        us8 o;
        o[0] = f2bf(v0[0]); o[1] = f2bf(v0[1]); o[2] = f2bf(v0[2]); o[3] = f2bf(v0[3]);
        o[4] = f2bf(v1[0]); o[5] = f2bf(v1[1]); o[6] = f2bf(v1[2]); o[7] = f2bf(v1[3]);
        *(us8*)(att + ((size_t)b * N_ + i0 + r) * C_ + h * HD + c * 8) = o;
    }
}

// ---------------- Kernel 4: proj GEMM (bf16 MFMA) + bias + residual ----------------
__global__ __launch_bounds__(256) void proj_gemm(const ushort* __restrict__ wp,
                                                 const ushort* __restrict__ att,
                                                 const float* __restrict__ bias,
                                                 const float* __restrict__ x,
                                                 float* __restrict__ out) {
    __shared__ struct { ushort As[64][72]; ushort Bs[128][72]; } s;
    int b = blockIdx.z, m0 = blockIdx.y * 64, n0 = blockIdx.x * 128;
    const ushort* Bsrc = att + (size_t)b * N_ * C_;
    int tid = threadIdx.x;
    int w = tid >> 6, lane = tid & 63;
    int g = lane >> 4, r16 = lane & 15;
    int wm = w >> 1, wn = w & 1;

    f32x4 acc[2][4];
    #pragma unroll
    for (int mf = 0; mf < 2; ++mf)
        #pragma unroll
        for (int nf = 0; nf < 4; ++nf) acc[mf][nf] = (f32x4){0.f, 0.f, 0.f, 0.f};

    for (int k0 = 0; k0 < 256; k0 += 64) {
        __syncthreads();
        #pragma unroll
        for (int it = 0; it < 2; ++it) {
            int t = it * 256 + tid, r = t >> 3, c = t & 7;
            *(us8*)&s.As[r][c * 8] = *(const us8*)(wp + (size_t)(m0 + r) * 256 + k0 + c * 8);
        }
        #pragma unroll
        for (int it = 0; it < 4; ++it) {
            int t = it * 256 + tid, r = t >> 3, c = t & 7;
            *(us8*)&s.Bs[r][c * 8] = *(const us8*)(Bsrc + (size_t)(n0 + r) * 256 + k0 + c * 8);
        }
        __syncthreads();
        bf16x8 aA[2][2], bB[4][2];
        #pragma unroll
        for (int mf = 0; mf < 2; ++mf)
            #pragma unroll
            for (int ks = 0; ks < 2; ++ks)
                aA[mf][ks] = *(const bf16x8*)&s.As[wm * 32 + mf * 16 + r16][ks * 32 + g * 8];
        #pragma unroll
        for (int nf = 0; nf < 4; ++nf)
            #pragma unroll
            for (int ks = 0; ks < 2; ++ks)
                bB[nf][ks] = *(const bf16x8*)&s.Bs[wn * 64 + nf * 16 + r16][ks * 32 + g * 8];
        #pragma unroll
        for (int ks = 0; ks < 2; ++ks)
            #pragma unroll
            for (int mf = 0; mf < 2; ++mf)
                #pragma unroll
                for (int nf = 0; nf < 4; ++nf)
                    acc[mf][nf] = __builtin_amdgcn_mfma_f32_16x16x32_bf16(aA[mf][ks], bB[nf][ks], acc[mf][nf], 0, 0, 0);
    }

    #pragma unroll
    for (int mf = 0; mf < 2; ++mf) {
        #pragma unroll
        for (int reg = 0; reg < 4; ++reg) {
            int c_ = m0 + wm * 32 + mf * 16 + g * 4 + reg;
            float bi = bias[c_];
            #pragma unroll
            for (int nf = 0; nf < 4; ++nf) {
                int n = n0 + wn * 64 + nf * 16 + r16;
                size_t o = ((size_t)b * C_ + c_) * N_ + n;
                out[o] = acc[mf][nf][reg] + bi + x[o];
            }
        }
    }
}

extern "C" void kernel_launch(void* const* d_in, const int* in_sizes, int n_in,
                              void* d_out, int out_size, void* d_ws, size_t ws_size,
                              hipStream_t stream) {
    const float* x      = (const float*)d_in[0];
    const float* gn_w   = (const float*)d_in[1];
    const float* gn_b   = (const float*)d_in[2];
    const float* qkv_w  = (const float*)d_in[3];
    const float* qkv_b  = (const float*)d_in[4];
    const float* proj_w = (const float*)d_in[5];
    const float* proj_b = (const float*)d_in[6];
    float* out = (float*)d_out;

    char* ws = (char*)d_ws;
    ushort* wq_bf = (ushort*)(ws);                               // 384 KB
    ushort* wp_bf = (ushort*)(ws + 393216);                      // 128 KB
    ushort* xnt   = (ushort*)(ws + (1u << 20));                  // 8 MB  [b][n][c]
    ushort* Qd    = (ushort*)(ws + (size_t)16 * 1024 * 1024);    // 8 MB  [b][h][n][d]
    ushort* Kd    = (ushort*)(ws + (size_t)24 * 1024 * 1024);    // 8 MB  [b][h][n][d]
    ushort* Vd    = (ushort*)(ws + (size_t)32 * 1024 * 1024);    // 8 MB  [b][h][d][n]
    ushort* att_t = (ushort*)(ws + (size_t)40 * 1024 * 1024);    // 8 MB  [b][n][c]

    prep_w<<<dim3(256), dim3(256), 0, stream>>>(qkv_w, proj_w, wq_bf, wp_bf);
    gn_kernel<<<dim3(B_ * 16), dim3(256), 0, stream>>>(x, gn_w, gn_b, xnt);
    qkv_gemm<<<dim3(8, 12, B_), dim3(256), 0, stream>>>(wq_bf, xnt, qkv_b, Qd, Kd, Vd);
    attn_mfma<<<dim3(512), dim3(256), 0, stream>>>(Qd, Kd, Vd, att_t);
    proj_gemm<<<dim3(8, 4, B_), dim3(256), 0, stream>>>(wp_bf, att_t, proj_b, x, out);
}

// Round 7
// 99.118 us; speedup vs baseline: 8.5202x; 1.2369x over previous
//
#include <hip/hip_runtime.h>
#include <math.h>

#define B_   16
#define C_   256
#define N_   1024
#define NH   4
#define HD   64
#define EPSV 1e-5f

typedef __attribute__((ext_vector_type(8))) short  bf16x8;
typedef __attribute__((ext_vector_type(8))) ushort us8;
typedef __attribute__((ext_vector_type(4))) float  f32x4;

__device__ inline ushort f2bf(float f) {
    union { float f; unsigned u; } v; v.f = f;
    unsigned r = v.u + 0x7fffu + ((v.u >> 16) & 1u);
    return (ushort)(r >> 16);
}

__device__ inline unsigned cvtpk(float lo, float hi) {
    unsigned r;
    asm("v_cvt_pk_bf16_f32 %0, %1, %2" : "=v"(r) : "v"(lo), "v"(hi));
    return r;
}

#define GLOAD16(gsrc, ldst) \
  __builtin_amdgcn_global_load_lds((const __attribute__((address_space(1))) unsigned int*)(gsrc), \
                                   (__attribute__((address_space(3))) unsigned int*)(ldst), 16, 0, 0)

// ---------------- Kernel 0: weight prep (f32 -> bf16) ----------------
__global__ __launch_bounds__(256) void prep_w(const float* __restrict__ qw,
                                              const float* __restrict__ pw,
                                              ushort* __restrict__ wq,
                                              ushort* __restrict__ wp) {
    int i = blockIdx.x * 256 + threadIdx.x;
    int T = gridDim.x * 256;
    for (int t = i; t < 49152; t += T) {
        float4 v = ((const float4*)qw)[t];
        ushort4 o; o.x = f2bf(v.x); o.y = f2bf(v.y); o.z = f2bf(v.z); o.w = f2bf(v.w);
        ((ushort4*)wq)[t] = o;
    }
    for (int t = i; t < 16384; t += T) {
        float4 v = ((const float4*)pw)[t];
        ushort4 o; o.x = f2bf(v.x); o.y = f2bf(v.y); o.z = f2bf(v.z); o.w = f2bf(v.w);
        ((ushort4*)wp)[t] = o;
    }
}

// ---------------- Kernel 1: GroupNorm -> bf16 transposed [b][n][c] ----------------
__global__ __launch_bounds__(256) void gn_kernel(const float* __restrict__ x,
                                                 const float* __restrict__ gw,
                                                 const float* __restrict__ gb,
                                                 ushort* __restrict__ xnt) {
    __shared__ ushort Ls[16][1028];
    __shared__ float redS[2][4], redQ[2][4], stats[2][2];
    int b = blockIdx.x >> 4, gp = blockIdx.x & 15;
    const float4* px4 = (const float4*)(x + ((size_t)b * C_ + gp * 16) * N_);
    int tid = threadIdx.x;

    float4 vals[16];
    float s0 = 0.f, q0 = 0.f, s1 = 0.f, q1 = 0.f;
    #pragma unroll
    for (int p = 0; p < 16; ++p) {
        float4 v = px4[p * 256 + tid];
        vals[p] = v;
        float ss = v.x + v.y + v.z + v.w;
        float qq = v.x * v.x + v.y * v.y + v.z * v.z + v.w * v.w;
        if (p < 8) { s0 += ss; q0 += qq; } else { s1 += ss; q1 += qq; }
    }
    #pragma unroll
    for (int off = 32; off; off >>= 1) {
        s0 += __shfl_down(s0, off); q0 += __shfl_down(q0, off);
        s1 += __shfl_down(s1, off); q1 += __shfl_down(q1, off);
    }
    int w = tid >> 6, lane = tid & 63;
    if (lane == 0) { redS[0][w] = s0; redQ[0][w] = q0; redS[1][w] = s1; redQ[1][w] = q1; }
    __syncthreads();
    if (tid < 2) {
        float S = redS[tid][0] + redS[tid][1] + redS[tid][2] + redS[tid][3];
        float Q = redQ[tid][0] + redQ[tid][1] + redQ[tid][2] + redQ[tid][3];
        float mean = S * (1.f / 8192.f);
        float var  = Q * (1.f / 8192.f) - mean * mean;
        stats[tid][0] = mean;
        stats[tid][1] = rsqrtf(var + EPSV);
    }
    __syncthreads();
    #pragma unroll
    for (int p = 0; p < 16; ++p) {
        int grp = p >> 3;
        int ch = gp * 16 + p;
        float ga = gw[ch] * stats[grp][1];
        float be = gb[ch] - stats[grp][0] * ga;
        float4 v = vals[p];
        ushort4 o;
        o.x = f2bf(v.x * ga + be); o.y = f2bf(v.y * ga + be);
        o.z = f2bf(v.z * ga + be); o.w = f2bf(v.w * ga + be);
        *(ushort4*)&Ls[p][tid * 4] = o;
    }
    __syncthreads();
    #pragma unroll
    for (int it = 0; it < 4; ++it) {
        int n = it * 256 + tid;
        us8 a, b2;
        #pragma unroll
        for (int c = 0; c < 8; ++c) { a[c] = Ls[c][n]; b2[c] = Ls[8 + c][n]; }
        ushort* dst = xnt + ((size_t)b * N_ + n) * C_ + gp * 16;
        *(us8*)dst = a;
        *(us8*)(dst + 8) = b2;
    }
}

// ---------------- Kernel 2: QKV GEMM (bf16 MFMA) ----------------
__global__ __launch_bounds__(256) void qkv_gemm(const ushort* __restrict__ wq,
                                                const ushort* __restrict__ xnt,
                                                const float* __restrict__ bias,
                                                ushort* __restrict__ Qd,
                                                ushort* __restrict__ Kd,
                                                ushort* __restrict__ Vd) {
    __shared__ union {
        struct { ushort As[64][72]; ushort Bs[128][72]; } s;
        ushort Ts[128][72];
    } u;
    int b = blockIdx.z, mt = blockIdx.y, n0 = blockIdx.x * 128;
    int s_ = mt >> 2, h = mt & 3;
    const ushort* Bsrc = xnt + (size_t)b * N_ * C_;
    int tid = threadIdx.x;
    int w = tid >> 6, lane = tid & 63;
    int g = lane >> 4, r16 = lane & 15;
    int wm = w >> 1, wn = w & 1;

    f32x4 acc[2][4];
    #pragma unroll
    for (int mf = 0; mf < 2; ++mf)
        #pragma unroll
        for (int nf = 0; nf < 4; ++nf) acc[mf][nf] = (f32x4){0.f, 0.f, 0.f, 0.f};

    for (int k0 = 0; k0 < 256; k0 += 64) {
        __syncthreads();
        #pragma unroll
        for (int it = 0; it < 2; ++it) {
            int t = it * 256 + tid, r = t >> 3, c = t & 7;
            *(us8*)&u.s.As[r][c * 8] = *(const us8*)(wq + (size_t)(mt * 64 + r) * 256 + k0 + c * 8);
        }
        #pragma unroll
        for (int it = 0; it < 4; ++it) {
            int t = it * 256 + tid, r = t >> 3, c = t & 7;
            *(us8*)&u.s.Bs[r][c * 8] = *(const us8*)(Bsrc + (size_t)(n0 + r) * 256 + k0 + c * 8);
        }
        __syncthreads();
        bf16x8 aA[2][2], bB[4][2];
        #pragma unroll
        for (int mf = 0; mf < 2; ++mf)
            #pragma unroll
            for (int ks = 0; ks < 2; ++ks)
                aA[mf][ks] = *(const bf16x8*)&u.s.As[wm * 32 + mf * 16 + r16][ks * 32 + g * 8];
        #pragma unroll
        for (int nf = 0; nf < 4; ++nf)
            #pragma unroll
            for (int ks = 0; ks < 2; ++ks)
                bB[nf][ks] = *(const bf16x8*)&u.s.Bs[wn * 64 + nf * 16 + r16][ks * 32 + g * 8];
        #pragma unroll
        for (int ks = 0; ks < 2; ++ks)
            #pragma unroll
            for (int mf = 0; mf < 2; ++mf)
                #pragma unroll
                for (int nf = 0; nf < 4; ++nf)
                    acc[mf][nf] = __builtin_amdgcn_mfma_f32_16x16x32_bf16(aA[mf][ks], bB[nf][ks], acc[mf][nf], 0, 0, 0);
    }
    __syncthreads();

    float scale = (s_ == 0) ? 0.125f : 1.f;
    float bfr[2][4];
    #pragma unroll
    for (int mf = 0; mf < 2; ++mf)
        #pragma unroll
        for (int reg = 0; reg < 4; ++reg)
            bfr[mf][reg] = bias[mt * 64 + wm * 32 + mf * 16 + g * 4 + reg];

    if (s_ < 2) {
        #pragma unroll
        for (int mf = 0; mf < 2; ++mf)
            #pragma unroll
            for (int nf = 0; nf < 4; ++nf)
                #pragma unroll
                for (int reg = 0; reg < 4; ++reg)
                    u.Ts[wn * 64 + nf * 16 + r16][wm * 32 + mf * 16 + g * 4 + reg] =
                        f2bf((acc[mf][nf][reg] + bfr[mf][reg]) * scale);
        __syncthreads();
        ushort* dst = (s_ == 0 ? Qd : Kd) + ((size_t)(b * NH + h) * N_ + n0) * HD;
        #pragma unroll
        for (int it = 0; it < 4; ++it) {
            int t = it * 256 + tid, r = t >> 3, c = t & 7;
            *(us8*)(dst + (size_t)r * HD + c * 8) = *(const us8*)&u.Ts[r][c * 8];
        }
    } else {
        #pragma unroll
        for (int mf = 0; mf < 2; ++mf)
            #pragma unroll
            for (int nf = 0; nf < 4; ++nf)
                #pragma unroll
                for (int reg = 0; reg < 4; ++reg) {
                    int d = wm * 32 + mf * 16 + g * 4 + reg;
                    int n = n0 + wn * 64 + nf * 16 + r16;
                    Vd[((size_t)(b * NH + h) * HD + d) * N_ + n] = f2bf(acc[mf][nf][reg] + bfr[mf][reg]);
                }
    }
}

// ---------------- Kernel 3: MFMA flash attention v4 ----------------
// Swapped QK^T (S^T = K*Q^T) -> in-register softmax + P exchange (no P LDS).
// K/V tiles [64][64] bf16 in LDS, chunk-XOR swizzle, staged via global_load_lds
// with pre-swizzled source. Double-buffered, 1 barrier/iter.
#define QT 128
#define KT 64
__global__ __launch_bounds__(256) void attn_mfma(const ushort* __restrict__ Qd,
                                                 const ushort* __restrict__ Kd,
                                                 const ushort* __restrict__ Vd,
                                                 ushort* __restrict__ att) {
    __shared__ union {
        struct { ushort Kb[2][64][64]; ushort Vb[2][64][64]; } s;
        float Op[128][68];
    } u;
    int nblk = blockIdx.x;
    int bh = nblk & 63, qt = nblk >> 6;
    int b = bh >> 2, h = bh & 3;
    int i0 = qt * QT;
    const ushort* qp = Qd + (size_t)bh * N_ * HD;
    const ushort* kp = Kd + (size_t)bh * N_ * HD;
    const ushort* vp = Vd + (size_t)bh * HD * N_;

    int tid = threadIdx.x;
    int w = tid >> 6, lane = tid & 63;
    int g = lane >> 4, r16 = lane & 15;
    int G = g >> 1, sbit = g & 1;
    int r7 = r16 & 7;

    // staging geometry: wave w stages rows [w*8, w*8+8) and +32 of each tile.
    int rwi = lane >> 3, cwi = lane & 7;
    int srow = w * 8 + rwi;
    int schk = cwi ^ rwi;               // pre-swizzled source chunk (involution)

    // Q fragments from global: q = i0 + w*32 + qf*16 + r16, 8 d per c-chunk
    bf16x8 aQ[2][2];
    #pragma unroll
    for (int qf = 0; qf < 2; ++qf)
        #pragma unroll
        for (int c = 0; c < 2; ++c)
            aQ[qf][c] = *(const bf16x8*)(qp + (size_t)(i0 + w * 32 + qf * 16 + r16) * HD + c * 32 + g * 8);

    float mrow[2], lsum[2];
    f32x4 oacc[2][4];
    #pragma unroll
    for (int qf = 0; qf < 2; ++qf) {
        mrow[qf] = -1e30f; lsum[qf] = 0.f;
        #pragma unroll
        for (int dt = 0; dt < 4; ++dt) oacc[qf][dt] = (f32x4){0.f, 0.f, 0.f, 0.f};
    }

    // prologue: stage tile 0 -> buf 0
    GLOAD16(kp + (size_t)srow * HD + schk * 8,        &u.s.Kb[0][w * 8][0]);
    GLOAD16(kp + (size_t)(srow + 32) * HD + schk * 8, &u.s.Kb[0][32 + w * 8][0]);
    GLOAD16(vp + (size_t)srow * N_ + schk * 8,        &u.s.Vb[0][w * 8][0]);
    GLOAD16(vp + (size_t)(srow + 32) * N_ + schk * 8, &u.s.Vb[0][32 + w * 8][0]);
    __syncthreads();

    for (int it = 0; it < 16; ++it) {
        int cur = it & 1;
        if (it < 15) {      // async prefetch tile it+1 into the other buffer
            int j0n = (it + 1) * KT;
            GLOAD16(kp + (size_t)(j0n + srow) * HD + schk * 8,        &u.s.Kb[cur ^ 1][w * 8][0]);
            GLOAD16(kp + (size_t)(j0n + srow + 32) * HD + schk * 8,   &u.s.Kb[cur ^ 1][32 + w * 8][0]);
            GLOAD16(vp + (size_t)srow * N_ + j0n + schk * 8,          &u.s.Vb[cur ^ 1][w * 8][0]);
            GLOAD16(vp + (size_t)(srow + 32) * N_ + j0n + schk * 8,   &u.s.Vb[cur ^ 1][32 + w * 8][0]);
        }

        // ---- QK^T swapped: sacc[qf][t], lane holds S[q=r16][k=t*16+g*4+r] ----
        f32x4 sacc[2][4];
        #pragma unroll
        for (int qf = 0; qf < 2; ++qf)
            #pragma unroll
            for (int t = 0; t < 4; ++t) sacc[qf][t] = (f32x4){0.f, 0.f, 0.f, 0.f};
        __builtin_amdgcn_s_setprio(1);
        #pragma unroll
        for (int t = 0; t < 4; ++t)
            #pragma unroll
            for (int c = 0; c < 2; ++c) {
                bf16x8 aK = *(const bf16x8*)&u.s.Kb[cur][t * 16 + r16][((g + 4 * c) ^ r7) * 8];
                #pragma unroll
                for (int qf = 0; qf < 2; ++qf)
                    sacc[qf][t] = __builtin_amdgcn_mfma_f32_16x16x32_bf16(aK, aQ[qf][c], sacc[qf][t], 0, 0, 0);
            }
        __builtin_amdgcn_s_setprio(0);

        // ---- in-register online softmax + P pack/exchange ----
        bf16x8 aP[2][2];
        int src0 = sbit * 32 + r16;
        int src1 = src0 + 16;
        int gi20 = g * 20;
        #pragma unroll
        for (int qf = 0; qf < 2; ++qf) {
            float mx = sacc[qf][0][0];
            #pragma unroll
            for (int t = 0; t < 4; ++t)
                #pragma unroll
                for (int r = 0; r < 4; ++r) mx = fmaxf(mx, sacc[qf][t][r]);
            mx = fmaxf(mx, __shfl_xor(mx, 16));
            mx = fmaxf(mx, __shfl_xor(mx, 32));
            float mn = fmaxf(mrow[qf], mx);
            float pv[4][4];
            float sum = 0.f;
            #pragma unroll
            for (int t = 0; t < 4; ++t)
                #pragma unroll
                for (int r = 0; r < 4; ++r) {
                    float e = __expf(sacc[qf][t][r] - mn);
                    pv[t][r] = e; sum += e;
                }
            sum += __shfl_xor(sum, 16);
            sum += __shfl_xor(sum, 32);
            float alpha = __expf(mrow[qf] - mn);
            mrow[qf] = mn;
            lsum[qf] = lsum[qf] * alpha + sum;
            #pragma unroll
            for (int r = 0; r < 4; ++r) {
                float alf = __shfl(alpha, gi20 + r);
                #pragma unroll
                for (int dt = 0; dt < 4; ++dt) oacc[qf][dt][r] *= alf;
            }
            unsigned pk_[4][2];
            #pragma unroll
            for (int t = 0; t < 4; ++t) {
                pk_[t][0] = cvtpk(pv[t][0], pv[t][1]);
                pk_[t][1] = cvtpk(pv[t][2], pv[t][3]);
            }
            #pragma unroll
            for (int c = 0; c < 2; ++c) {
                unsigned aA0 = (unsigned)__shfl((int)pk_[2 * c][0], src0);
                unsigned aB0 = (unsigned)__shfl((int)pk_[2 * c + 1][0], src0);
                unsigned aA1 = (unsigned)__shfl((int)pk_[2 * c][1], src0);
                unsigned aB1 = (unsigned)__shfl((int)pk_[2 * c + 1][1], src0);
                unsigned aA2 = (unsigned)__shfl((int)pk_[2 * c][0], src1);
                unsigned aB2 = (unsigned)__shfl((int)pk_[2 * c + 1][0], src1);
                unsigned aA3 = (unsigned)__shfl((int)pk_[2 * c][1], src1);
                unsigned aB3 = (unsigned)__shfl((int)pk_[2 * c + 1][1], src1);
                union { unsigned u4[4]; bf16x8 v; } ap;
                ap.u4[0] = G ? aB0 : aA0;
                ap.u4[1] = G ? aB1 : aA1;
                ap.u4[2] = G ? aB2 : aA2;
                ap.u4[3] = G ? aB3 : aA3;
                aP[qf][c] = ap.v;
            }
        }

        // ---- PV: O[q][d] ----
        __builtin_amdgcn_s_setprio(1);
        #pragma unroll
        for (int dt = 0; dt < 4; ++dt)
            #pragma unroll
            for (int c = 0; c < 2; ++c) {
                bf16x8 bV = *(const bf16x8*)&u.s.Vb[cur][dt * 16 + r16][((g + 4 * c) ^ r7) * 8];
                #pragma unroll
                for (int qf = 0; qf < 2; ++qf)
                    oacc[qf][dt] = __builtin_amdgcn_mfma_f32_16x16x32_bf16(aP[qf][c], bV, oacc[qf][dt], 0, 0, 0);
            }
        __builtin_amdgcn_s_setprio(0);

        __syncthreads();   // drains prefetch (vmcnt) + all waves done reading buf[cur]
    }

    // ---- epilogue: normalize (l via shfl), transpose via LDS, bf16 store ----
    int gi20e = g * 20;
    #pragma unroll
    for (int qf = 0; qf < 2; ++qf) {
        float linv[4];
        #pragma unroll
        for (int r = 0; r < 4; ++r) linv[r] = 1.f / __shfl(lsum[qf], gi20e + r);
        #pragma unroll
        for (int dt = 0; dt < 4; ++dt)
            #pragma unroll
            for (int r = 0; r < 4; ++r)
                u.Op[w * 32 + qf * 16 + g * 4 + r][dt * 16 + r16] = oacc[qf][dt][r] * linv[r];
    }
    __syncthreads();

    #pragma unroll
    for (int it = 0; it < 4; ++it) {
        int t = it * 256 + tid;
        int r = t >> 3, c = t & 7;
        f32x4 v0 = *(const f32x4*)&u.Op[r][c * 8];
        f32x4 v1 = *(const f32x4*)&u.Op[r][c * 8 + 4];
        us8 o;
        o[0] = f2bf(v0[0]); o[1] = f2bf(v0[1]); o[2] = f2bf(v0[2]); o[3] = f2bf(v0[3]);
        o[4] = f2bf(v1[0]); o[5] = f2bf(v1[1]); o[6] = f2bf(v1[2]); o[7] = f2bf(v1[3]);
        *(us8*)(att + ((size_t)b * N_ + i0 + r) * C_ + h * HD + c * 8) = o;
    }
}

// ---------------- Kernel 4: proj GEMM (bf16 MFMA) + bias + residual ----------------
__global__ __launch_bounds__(256) void proj_gemm(const ushort* __restrict__ wp,
                                                 const ushort* __restrict__ att,
                                                 const float* __restrict__ bias,
                                                 const float* __restrict__ x,
                                                 float* __restrict__ out) {
    __shared__ struct { ushort As[64][72]; ushort Bs[128][72]; } s;
    int b = blockIdx.z, m0 = blockIdx.y * 64, n0 = blockIdx.x * 128;
    const ushort* Bsrc = att + (size_t)b * N_ * C_;
    int tid = threadIdx.x;
    int w = tid >> 6, lane = tid & 63;
    int g = lane >> 4, r16 = lane & 15;
    int wm = w >> 1, wn = w & 1;

    f32x4 acc[2][4];
    #pragma unroll
    for (int mf = 0; mf < 2; ++mf)
        #pragma unroll
        for (int nf = 0; nf < 4; ++nf) acc[mf][nf] = (f32x4){0.f, 0.f, 0.f, 0.f};

    for (int k0 = 0; k0 < 256; k0 += 64) {
        __syncthreads();
        #pragma unroll
        for (int it = 0; it < 2; ++it) {
            int t = it * 256 + tid, r = t >> 3, c = t & 7;
            *(us8*)&s.As[r][c * 8] = *(const us8*)(wp + (size_t)(m0 + r) * 256 + k0 + c * 8);
        }
        #pragma unroll
        for (int it = 0; it < 4; ++it) {
            int t = it * 256 + tid, r = t >> 3, c = t & 7;
            *(us8*)&s.Bs[r][c * 8] = *(const us8*)(Bsrc + (size_t)(n0 + r) * 256 + k0 + c * 8);
        }
        __syncthreads();
        bf16x8 aA[2][2], bB[4][2];
        #pragma unroll
        for (int mf = 0; mf < 2; ++mf)
            #pragma unroll
            for (int ks = 0; ks < 2; ++ks)
                aA[mf][ks] = *(const bf16x8*)&s.As[wm * 32 + mf * 16 + r16][ks * 32 + g * 8];
        #pragma unroll
        for (int nf = 0; nf < 4; ++nf)
            #pragma unroll
            for (int ks = 0; ks < 2; ++ks)
                bB[nf][ks] = *(const bf16x8*)&s.Bs[wn * 64 + nf * 16 + r16][ks * 32 + g * 8];
        #pragma unroll
        for (int ks = 0; ks < 2; ++ks)
            #pragma unroll
            for (int mf = 0; mf < 2; ++mf)
                #pragma unroll
                for (int nf = 0; nf < 4; ++nf)
                    acc[mf][nf] = __builtin_amdgcn_mfma_f32_16x16x32_bf16(aA[mf][ks], bB[nf][ks], acc[mf][nf], 0, 0, 0);
    }

    #pragma unroll
    for (int mf = 0; mf < 2; ++mf) {
        #pragma unroll
        for (int reg = 0; reg < 4; ++reg) {
            int c_ = m0 + wm * 32 + mf * 16 + g * 4 + reg;
            float bi = bias[c_];
            #pragma unroll
            for (int nf = 0; nf < 4; ++nf) {
                int n = n0 + wn * 64 + nf * 16 + r16;
                size_t o = ((size_t)b * C_ + c_) * N_ + n;
                out[o] = acc[mf][nf][reg] + bi + x[o];
            }
        }
    }
}

extern "C" void kernel_launch(void* const* d_in, const int* in_sizes, int n_in,
                              void* d_out, int out_size, void* d_ws, size_t ws_size,
                              hipStream_t stream) {
    const float* x      = (const float*)d_in[0];
    const float* gn_w   = (const float*)d_in[1];
    const float* gn_b   = (const float*)d_in[2];
    const float* qkv_w  = (const float*)d_in[3];
    const float* qkv_b  = (const float*)d_in[4];
    const float* proj_w = (const float*)d_in[5];
    const float* proj_b = (const float*)d_in[6];
    float* out = (float*)d_out;

    char* ws = (char*)d_ws;
    ushort* wq_bf = (ushort*)(ws);                               // 384 KB
    ushort* wp_bf = (ushort*)(ws + 393216);                      // 128 KB
    ushort* xnt   = (ushort*)(ws + (1u << 20));                  // 8 MB  [b][n][c]
    ushort* Qd    = (ushort*)(ws + (size_t)16 * 1024 * 1024);    // 8 MB  [b][h][n][d]
    ushort* Kd    = (ushort*)(ws + (size_t)24 * 1024 * 1024);    // 8 MB  [b][h][n][d]
    ushort* Vd    = (ushort*)(ws + (size_t)32 * 1024 * 1024);    // 8 MB  [b][h][d][n]
    ushort* att_t = (ushort*)(ws + (size_t)40 * 1024 * 1024);    // 8 MB  [b][n][c]

    prep_w<<<dim3(256), dim3(256), 0, stream>>>(qkv_w, proj_w, wq_bf, wp_bf);
    gn_kernel<<<dim3(B_ * 16), dim3(256), 0, stream>>>(x, gn_w, gn_b, xnt);
    qkv_gemm<<<dim3(8, 12, B_), dim3(256), 0, stream>>>(wq_bf, xnt, qkv_b, Qd, Kd, Vd);
    attn_mfma<<<dim3(512), dim3(256), 0, stream>>>(Qd, Kd, Vd, att_t);
    proj_gemm<<<dim3(8, 4, B_), dim3(256), 0, stream>>>(wp_bf, att_t, proj_b, x, out);
}

// Round 9
// 91.442 us; speedup vs baseline: 9.2355x; 1.0839x over previous
//
#include <hip/hip_runtime.h>
#include <math.h>

#define B_   16
#define C_   256
#define N_   1024
#define NH   4
#define HD   64
#define EPSV 1e-5f
#define LOG2E 1.44269504088896f

typedef __attribute__((ext_vector_type(8)))  short  bf16x8;
typedef __attribute__((ext_vector_type(8)))  ushort us8;
typedef __attribute__((ext_vector_type(4)))  float  f32x4;
typedef __attribute__((ext_vector_type(16))) float  f32x16;

__device__ inline ushort f2bf(float f) {
    union { float f; unsigned u; } v; v.f = f;
    unsigned r = v.u + 0x7fffu + ((v.u >> 16) & 1u);
    return (ushort)(r >> 16);
}

__device__ inline unsigned cvtpk(float lo, float hi) {
    unsigned r;
    asm("v_cvt_pk_bf16_f32 %0, %1, %2" : "=v"(r) : "v"(lo), "v"(hi));
    return r;
}

#define GLOAD16(gsrc, ldst) \
  __builtin_amdgcn_global_load_lds((const __attribute__((address_space(1))) unsigned int*)(gsrc), \
                                   (__attribute__((address_space(3))) unsigned int*)(ldst), 16, 0, 0)

// ---------------- Kernel 0: weight prep (f32 -> bf16) ----------------
__global__ __launch_bounds__(256) void prep_w(const float* __restrict__ qw,
                                              const float* __restrict__ pw,
                                              ushort* __restrict__ wq,
                                              ushort* __restrict__ wp) {
    int i = blockIdx.x * 256 + threadIdx.x;
    int T = gridDim.x * 256;
    for (int t = i; t < 49152; t += T) {
        float4 v = ((const float4*)qw)[t];
        ushort4 o; o.x = f2bf(v.x); o.y = f2bf(v.y); o.z = f2bf(v.z); o.w = f2bf(v.w);
        ((ushort4*)wq)[t] = o;
    }
    for (int t = i; t < 16384; t += T) {
        float4 v = ((const float4*)pw)[t];
        ushort4 o; o.x = f2bf(v.x); o.y = f2bf(v.y); o.z = f2bf(v.z); o.w = f2bf(v.w);
        ((ushort4*)wp)[t] = o;
    }
}

// ---------------- Kernel 1: GroupNorm -> bf16 transposed [b][n][c] ----------------
__global__ __launch_bounds__(256) void gn_kernel(const float* __restrict__ x,
                                                 const float* __restrict__ gw,
                                                 const float* __restrict__ gb,
                                                 ushort* __restrict__ xnt) {
    __shared__ ushort Ls[16][1028];
    __shared__ float redS[2][4], redQ[2][4], stats[2][2];
    int b = blockIdx.x >> 4, gp = blockIdx.x & 15;
    const float4* px4 = (const float4*)(x + ((size_t)b * C_ + gp * 16) * N_);
    int tid = threadIdx.x;

    float4 vals[16];
    float s0 = 0.f, q0 = 0.f, s1 = 0.f, q1 = 0.f;
    #pragma unroll
    for (int p = 0; p < 16; ++p) {
        float4 v = px4[p * 256 + tid];
        vals[p] = v;
        float ss = v.x + v.y + v.z + v.w;
        float qq = v.x * v.x + v.y * v.y + v.z * v.z + v.w * v.w;
        if (p < 8) { s0 += ss; q0 += qq; } else { s1 += ss; q1 += qq; }
    }
    #pragma unroll
    for (int off = 32; off; off >>= 1) {
        s0 += __shfl_down(s0, off); q0 += __shfl_down(q0, off);
        s1 += __shfl_down(s1, off); q1 += __shfl_down(q1, off);
    }
    int w = tid >> 6, lane = tid & 63;
    if (lane == 0) { redS[0][w] = s0; redQ[0][w] = q0; redS[1][w] = s1; redQ[1][w] = q1; }
    __syncthreads();
    if (tid < 2) {
        float S = redS[tid][0] + redS[tid][1] + redS[tid][2] + redS[tid][3];
        float Q = redQ[tid][0] + redQ[tid][1] + redQ[tid][2] + redQ[tid][3];
        float mean = S * (1.f / 8192.f);
        float var  = Q * (1.f / 8192.f) - mean * mean;
        stats[tid][0] = mean;
        stats[tid][1] = rsqrtf(var + EPSV);
    }
    __syncthreads();
    #pragma unroll
    for (int p = 0; p < 16; ++p) {
        int grp = p >> 3;
        int ch = gp * 16 + p;
        float ga = gw[ch] * stats[grp][1];
        float be = gb[ch] - stats[grp][0] * ga;
        float4 v = vals[p];
        ushort4 o;
        o.x = f2bf(v.x * ga + be); o.y = f2bf(v.y * ga + be);
        o.z = f2bf(v.z * ga + be); o.w = f2bf(v.w * ga + be);
        *(ushort4*)&Ls[p][tid * 4] = o;
    }
    __syncthreads();
    #pragma unroll
    for (int it = 0; it < 4; ++it) {
        int n = it * 256 + tid;
        us8 a, b2;
        #pragma unroll
        for (int c = 0; c < 8; ++c) { a[c] = Ls[c][n]; b2[c] = Ls[8 + c][n]; }
        ushort* dst = xnt + ((size_t)b * N_ + n) * C_ + gp * 16;
        *(us8*)dst = a;
        *(us8*)(dst + 8) = b2;
    }
}

// ---------------- Kernel 2: QKV GEMM (bf16 MFMA) ----------------
// Q scale folds 0.125 * log2(e)  (attention softmax runs in exp2 domain).
__global__ __launch_bounds__(256) void qkv_gemm(const ushort* __restrict__ wq,
                                                const ushort* __restrict__ xnt,
                                                const float* __restrict__ bias,
                                                ushort* __restrict__ Qd,
                                                ushort* __restrict__ Kd,
                                                ushort* __restrict__ Vd) {
    __shared__ union {
        struct { ushort As[64][72]; ushort Bs[128][72]; } s;
        ushort Ts[128][72];
    } u;
    int b = blockIdx.z, mt = blockIdx.y, n0 = blockIdx.x * 128;
    int s_ = mt >> 2, h = mt & 3;
    const ushort* Bsrc = xnt + (size_t)b * N_ * C_;
    int tid = threadIdx.x;
    int w = tid >> 6, lane = tid & 63;
    int g = lane >> 4, r16 = lane & 15;
    int wm = w >> 1, wn = w & 1;

    f32x4 acc[2][4];
    #pragma unroll
    for (int mf = 0; mf < 2; ++mf)
        #pragma unroll
        for (int nf = 0; nf < 4; ++nf) acc[mf][nf] = (f32x4){0.f, 0.f, 0.f, 0.f};

    for (int k0 = 0; k0 < 256; k0 += 64) {
        __syncthreads();
        #pragma unroll
        for (int it = 0; it < 2; ++it) {
            int t = it * 256 + tid, r = t >> 3, c = t & 7;
            *(us8*)&u.s.As[r][c * 8] = *(const us8*)(wq + (size_t)(mt * 64 + r) * 256 + k0 + c * 8);
        }
        #pragma unroll
        for (int it = 0; it < 4; ++it) {
            int t = it * 256 + tid, r = t >> 3, c = t & 7;
            *(us8*)&u.s.Bs[r][c * 8] = *(const us8*)(Bsrc + (size_t)(n0 + r) * 256 + k0 + c * 8);
        }
        __syncthreads();
        bf16x8 aA[2][2], bB[4][2];
        #pragma unroll
        for (int mf = 0; mf < 2; ++mf)
            #pragma unroll
            for (int ks = 0; ks < 2; ++ks)
                aA[mf][ks] = *(const bf16x8*)&u.s.As[wm * 32 + mf * 16 + r16][ks * 32 + g * 8];
        #pragma unroll
        for (int nf = 0; nf < 4; ++nf)
            #pragma unroll
            for (int ks = 0; ks < 2; ++ks)
                bB[nf][ks] = *(const bf16x8*)&u.s.Bs[wn * 64 + nf * 16 + r16][ks * 32 + g * 8];
        #pragma unroll
        for (int ks = 0; ks < 2; ++ks)
            #pragma unroll
            for (int mf = 0; mf < 2; ++mf)
                #pragma unroll
                for (int nf = 0; nf < 4; ++nf)
                    acc[mf][nf] = __builtin_amdgcn_mfma_f32_16x16x32_bf16(aA[mf][ks], bB[nf][ks], acc[mf][nf], 0, 0, 0);
    }
    __syncthreads();

    float scale = (s_ == 0) ? 0.125f * LOG2E : 1.f;
    float bfr[2][4];
    #pragma unroll
    for (int mf = 0; mf < 2; ++mf)
        #pragma unroll
        for (int reg = 0; reg < 4; ++reg)
            bfr[mf][reg] = bias[mt * 64 + wm * 32 + mf * 16 + g * 4 + reg];

    if (s_ < 2) {
        #pragma unroll
        for (int mf = 0; mf < 2; ++mf)
            #pragma unroll
            for (int nf = 0; nf < 4; ++nf)
                #pragma unroll
                for (int reg = 0; reg < 4; ++reg)
                    u.Ts[wn * 64 + nf * 16 + r16][wm * 32 + mf * 16 + g * 4 + reg] =
                        f2bf((acc[mf][nf][reg] + bfr[mf][reg]) * scale);
        __syncthreads();
        ushort* dst = (s_ == 0 ? Qd : Kd) + ((size_t)(b * NH + h) * N_ + n0) * HD;
        #pragma unroll
        for (int it = 0; it < 4; ++it) {
            int t = it * 256 + tid, r = t >> 3, c = t & 7;
            *(us8*)(dst + (size_t)r * HD + c * 8) = *(const us8*)&u.Ts[r][c * 8];
        }
    } else {
        #pragma unroll
        for (int mf = 0; mf < 2; ++mf)
            #pragma unroll
            for (int nf = 0; nf < 4; ++nf)
                #pragma unroll
                for (int reg = 0; reg < 4; ++reg) {
                    int d = wm * 32 + mf * 16 + g * 4 + reg;
                    int n = n0 + wn * 64 + nf * 16 + r16;
                    Vd[((size_t)(b * NH + h) * HD + d) * N_ + n] = f2bf(acc[mf][nf][reg] + bfr[mf][reg]);
                }
    }
}

// ---------------- Kernel 3: MFMA flash attention v5 (32x32 MFMA) ----------------
// grid 1024: bh = n&63, qt = n>>6 (16 q-tiles of 64). 128 threads = 2 waves x 32q.
// Swapped QK^T (32x32x16), in-register softmax (exp2 domain, defer-max THR=8),
// single xor-32 butterfly P exchange, GLOAD16-swizzled K/V double buffer.
#define KT 64
__global__ __launch_bounds__(128) void attn_mfma(const ushort* __restrict__ Qd,
                                                 const ushort* __restrict__ Kd,
                                                 const ushort* __restrict__ Vd,
                                                 ushort* __restrict__ att) {
    __shared__ union {
        struct { ushort Kb[2][64][64]; ushort Vb[2][64][64]; } s;
        float Op[64][68];
    } u;
    __shared__ float Lsh[64];
    int nblk = blockIdx.x;
    int bh = nblk & 63, qt = nblk >> 6;
    int b = bh >> 2, head = bh & 3;
    int i0 = qt * 64;
    const ushort* qp = Qd + (size_t)bh * N_ * HD;
    const ushort* kp = Kd + (size_t)bh * N_ * HD;
    const ushort* vp = Vd + (size_t)bh * HD * N_;

    int tid = threadIdx.x;
    int w = tid >> 6, lane = tid & 63;
    int hl = lane >> 5, r32 = lane & 31;
    int r7 = r32 & 7;
    int rwi = lane >> 3, cwi = lane & 7;
    int schk = cwi ^ (rwi & 7);          // pre-swizzled source chunk (involution)

    // Q B-fragments: B[d = c*16 + 8*hl + j][q = r32], q_glob = i0 + w*32 + r32
    bf16x8 aQ[4];
    {
        const ushort* qrow = qp + (size_t)(i0 + w * 32 + r32) * HD;
        #pragma unroll
        for (int c = 0; c < 4; ++c)
            aQ[c] = *(const bf16x8*)(qrow + c * 16 + hl * 8);
    }

    float m = -1e30f, l = 0.f;
    f32x16 oacc[2];
    #pragma unroll
    for (int dt = 0; dt < 2; ++dt)
        #pragma unroll
        for (int i = 0; i < 16; ++i) oacc[dt][i] = 0.f;

    // prologue: stage tile 0 -> buf 0 (wave w stages rows p*16 + w*8 .. +8)
    #pragma unroll
    for (int p = 0; p < 4; ++p) {
        int row = p * 16 + w * 8 + rwi;
        GLOAD16(kp + (size_t)row * HD + schk * 8, &u.s.Kb[0][p * 16 + w * 8][0]);
        GLOAD16(vp + (size_t)row * N_ + schk * 8, &u.s.Vb[0][p * 16 + w * 8][0]);
    }
    __syncthreads();

    for (int it = 0; it < 16; ++it) {
        int cur = it & 1;
        if (it < 15) {   // async prefetch next tile into the other buffer
            int j0n = (it + 1) * KT;
            #pragma unroll
            for (int p = 0; p < 4; ++p) {
                int row = p * 16 + w * 8 + rwi;
                GLOAD16(kp + (size_t)(j0n + row) * HD + schk * 8, &u.s.Kb[cur ^ 1][p * 16 + w * 8][0]);
                GLOAD16(vp + (size_t)row * N_ + j0n + schk * 8,   &u.s.Vb[cur ^ 1][p * 16 + w * 8][0]);
            }
        }

        // ---- QK^T swapped (32x32x16): sacc[t]: S^T[k = (reg&3)+8(reg>>2)+4hl + 32t][q = r32]
        f32x16 sacc[2];
        #pragma unroll
        for (int t = 0; t < 2; ++t)
            #pragma unroll
            for (int i = 0; i < 16; ++i) sacc[t][i] = 0.f;
        __builtin_amdgcn_s_setprio(1);
        #pragma unroll
        for (int t = 0; t < 2; ++t)
            #pragma unroll
            for (int c = 0; c < 4; ++c) {
                bf16x8 aK = *(const bf16x8*)&u.s.Kb[cur][t * 32 + r32][((2 * c + hl) ^ r7) * 8];
                sacc[t] = __builtin_amdgcn_mfma_f32_32x32x16_bf16(aK, aQ[c], sacc[t], 0, 0, 0);
            }
        __builtin_amdgcn_s_setprio(0);

        // ---- online softmax in exp2 domain, defer-max (THR=8) ----
        float mx = sacc[0][0];
        #pragma unroll
        for (int t = 0; t < 2; ++t)
            #pragma unroll
            for (int i = 0; i < 16; ++i) mx = fmaxf(mx, sacc[t][i]);
        mx = fmaxf(mx, __shfl_xor(mx, 32));
        if (!__all(mx - m <= 8.f)) {          // rare: iter 0 (+ ~never after)
            float mn = fmaxf(m, mx);
            float alpha = exp2f(m - mn);
            l *= alpha;
            m = mn;
            #pragma unroll
            for (int R = 0; R < 4; ++R)
                #pragma unroll
                for (int rr = 0; rr < 4; ++rr) {
                    float alf = __shfl(alpha, rr + 8 * R + 4 * hl);
                    oacc[0][R * 4 + rr] *= alf;
                    oacc[1][R * 4 + rr] *= alf;
                }
        }
        float p0[16], p1[16];
        float sum = 0.f;
        #pragma unroll
        for (int i = 0; i < 16; ++i) { p0[i] = exp2f(sacc[0][i] - m); sum += p0[i]; }
        #pragma unroll
        for (int i = 0; i < 16; ++i) { p1[i] = exp2f(sacc[1][i] - m); sum += p1[i]; }
        sum += __shfl_xor(sum, 32);
        l += sum;

        // ---- pack P to bf16 pairs; single xor-32 butterfly -> A-fragments ----
        unsigned pk0[4][2], pk1[4][2];
        #pragma unroll
        for (int R = 0; R < 4; ++R) {
            pk0[R][0] = cvtpk(p0[R * 4 + 0], p0[R * 4 + 1]);
            pk0[R][1] = cvtpk(p0[R * 4 + 2], p0[R * 4 + 3]);
            pk1[R][0] = cvtpk(p1[R * 4 + 0], p1[R * 4 + 1]);
            pk1[R][1] = cvtpk(p1[R * 4 + 2], p1[R * 4 + 3]);
        }
        bool hb = (hl == 1);
        unsigned apk[4][4];     // [kt][delta]: k = 16kt + 8hl + 2*delta
        #pragma unroll
        for (int t = 0; t < 2; ++t)
            #pragma unroll
            for (int s2 = 0; s2 < 2; ++s2) {
                int kt = 2 * t + s2;
                unsigned a0 = t ? pk1[2 * s2][0]     : pk0[2 * s2][0];
                unsigned a1 = t ? pk1[2 * s2][1]     : pk0[2 * s2][1];
                unsigned b0 = t ? pk1[2 * s2 + 1][0] : pk0[2 * s2 + 1][0];
                unsigned b1 = t ? pk1[2 * s2 + 1][1] : pk0[2 * s2 + 1][1];
                unsigned g0 = (unsigned)__shfl_xor((int)(hb ? a0 : b0), 32);
                unsigned g1 = (unsigned)__shfl_xor((int)(hb ? a1 : b1), 32);
                apk[kt][0] = hb ? g0 : a0;
                apk[kt][1] = hb ? g1 : a1;
                apk[kt][2] = hb ? b0 : g0;
                apk[kt][3] = hb ? b1 : g1;
            }

        // ---- PV (32x32x16): oacc[dt] over d = dt*32 + r32 ----
        __builtin_amdgcn_s_setprio(1);
        #pragma unroll
        for (int kt = 0; kt < 4; ++kt) {
            union { unsigned uu[4]; bf16x8 v; } ap;
            ap.uu[0] = apk[kt][0]; ap.uu[1] = apk[kt][1];
            ap.uu[2] = apk[kt][2]; ap.uu[3] = apk[kt][3];
            #pragma unroll
            for (int dt = 0; dt < 2; ++dt) {
                bf16x8 bV = *(const bf16x8*)&u.s.Vb[cur][dt * 32 + r32][((2 * kt + hl) ^ r7) * 8];
                oacc[dt] = __builtin_amdgcn_mfma_f32_32x32x16_bf16(ap.v, bV, oacc[dt], 0, 0, 0);
            }
        }
        __builtin_amdgcn_s_setprio(0);

        __syncthreads();   // drains prefetch vmcnt + all waves done with buf[cur]
    }

    // ---- epilogue: raw O -> LDS transpose, normalize on store ----
    if (hl == 0) Lsh[w * 32 + r32] = 1.f / l;
    #pragma unroll
    for (int dt = 0; dt < 2; ++dt)
        #pragma unroll
        for (int reg = 0; reg < 16; ++reg)
            u.Op[w * 32 + (reg & 3) + 8 * (reg >> 2) + 4 * hl][dt * 32 + r32] = oacc[dt][reg];
    __syncthreads();

    #pragma unroll
    for (int it = 0; it < 4; ++it) {
        int t = it * 128 + tid;
        int r = t >> 3, c = t & 7;          // 64 rows x 8 chunks of 8 d
        float linv = Lsh[r];
        f32x4 v0 = *(const f32x4*)&u.Op[r][c * 8];
        f32x4 v1 = *(const f32x4*)&u.Op[r][c * 8 + 4];
        union { unsigned uu[4]; us8 v; } ov;
        ov.uu[0] = cvtpk(v0[0] * linv, v0[1] * linv);
        ov.uu[1] = cvtpk(v0[2] * linv, v0[3] * linv);
        ov.uu[2] = cvtpk(v1[0] * linv, v1[1] * linv);
        ov.uu[3] = cvtpk(v1[2] * linv, v1[3] * linv);
        *(us8*)(att + ((size_t)b * N_ + i0 + r) * C_ + head * HD + c * 8) = ov.v;
    }
}

// ---------------- Kernel 4: proj GEMM (bf16 MFMA) + bias + residual ----------------
__global__ __launch_bounds__(256) void proj_gemm(const ushort* __restrict__ wp,
                                                 const ushort* __restrict__ att,
                                                 const float* __restrict__ bias,
                                                 const float* __restrict__ x,
                                                 float* __restrict__ out) {
    __shared__ struct { ushort As[64][72]; ushort Bs[128][72]; } s;
    int b = blockIdx.z, m0 = blockIdx.y * 64, n0 = blockIdx.x * 128;
    const ushort* Bsrc = att + (size_t)b * N_ * C_;
    int tid = threadIdx.x;
    int w = tid >> 6, lane = tid & 63;
    int g = lane >> 4, r16 = lane & 15;
    int wm = w >> 1, wn = w & 1;

    f32x4 acc[2][4];
    #pragma unroll
    for (int mf = 0; mf < 2; ++mf)
        #pragma unroll
        for (int nf = 0; nf < 4; ++nf) acc[mf][nf] = (f32x4){0.f, 0.f, 0.f, 0.f};

    for (int k0 = 0; k0 < 256; k0 += 64) {
        __syncthreads();
        #pragma unroll
        for (int it = 0; it < 2; ++it) {
            int t = it * 256 + tid, r = t >> 3, c = t & 7;
            *(us8*)&s.As[r][c * 8] = *(const us8*)(wp + (size_t)(m0 + r) * 256 + k0 + c * 8);
        }
        #pragma unroll
        for (int it = 0; it < 4; ++it) {
            int t = it * 256 + tid, r = t >> 3, c = t & 7;
            *(us8*)&s.Bs[r][c * 8] = *(const us8*)(Bsrc + (size_t)(n0 + r) * 256 + k0 + c * 8);
        }
        __syncthreads();
        bf16x8 aA[2][2], bB[4][2];
        #pragma unroll
        for (int mf = 0; mf < 2; ++mf)
            #pragma unroll
            for (int ks = 0; ks < 2; ++ks)
                aA[mf][ks] = *(const bf16x8*)&s.As[wm * 32 + mf * 16 + r16][ks * 32 + g * 8];
        #pragma unroll
        for (int nf = 0; nf < 4; ++nf)
            #pragma unroll
            for (int ks = 0; ks < 2; ++ks)
                bB[nf][ks] = *(const bf16x8*)&s.Bs[wn * 64 + nf * 16 + r16][ks * 32 + g * 8];
        #pragma unroll
        for (int ks = 0; ks < 2; ++ks)
            #pragma unroll
            for (int mf = 0; mf < 2; ++mf)
                #pragma unroll
                for (int nf = 0; nf < 4; ++nf)
                    acc[mf][nf] = __builtin_amdgcn_mfma_f32_16x16x32_bf16(aA[mf][ks], bB[nf][ks], acc[mf][nf], 0, 0, 0);
    }

    #pragma unroll
    for (int mf = 0; mf < 2; ++mf) {
        #pragma unroll
        for (int reg = 0; reg < 4; ++reg) {
            int c_ = m0 + wm * 32 + mf * 16 + g * 4 + reg;
            float bi = bias[c_];
            #pragma unroll
            for (int nf = 0; nf < 4; ++nf) {
                int n = n0 + wn * 64 + nf * 16 + r16;
                size_t o = ((size_t)b * C_ + c_) * N_ + n;
                out[o] = acc[mf][nf][reg] + bi + x[o];
            }
        }
    }
}

extern "C" void kernel_launch(void* const* d_in, const int* in_sizes, int n_in,
                              void* d_out, int out_size, void* d_ws, size_t ws_size,
                              hipStream_t stream) {
    const float* x      = (const float*)d_in[0];
    const float* gn_w   = (const float*)d_in[1];
    const float* gn_b   = (const float*)d_in[2];
    const float* qkv_w  = (const float*)d_in[3];
    const float* qkv_b  = (const float*)d_in[4];
    const float* proj_w = (const float*)d_in[5];
    const float* proj_b = (const float*)d_in[6];
    float* out = (float*)d_out;

    char* ws = (char*)d_ws;
    ushort* wq_bf = (ushort*)(ws);                               // 384 KB
    ushort* wp_bf = (ushort*)(ws + 393216);                      // 128 KB
    ushort* xnt   = (ushort*)(ws + (1u << 20));                  // 8 MB  [b][n][c]
    ushort* Qd    = (ushort*)(ws + (size_t)16 * 1024 * 1024);    // 8 MB  [b][h][n][d]
    ushort* Kd    = (ushort*)(ws + (size_t)24 * 1024 * 1024);    // 8 MB  [b][h][n][d]
    ushort* Vd    = (ushort*)(ws + (size_t)32 * 1024 * 1024);    // 8 MB  [b][h][d][n]
    ushort* att_t = (ushort*)(ws + (size_t)40 * 1024 * 1024);    // 8 MB  [b][n][c]

    prep_w<<<dim3(256), dim3(256), 0, stream>>>(qkv_w, proj_w, wq_bf, wp_bf);
    gn_kernel<<<dim3(B_ * 16), dim3(256), 0, stream>>>(x, gn_w, gn_b, xnt);
    qkv_gemm<<<dim3(8, 12, B_), dim3(256), 0, stream>>>(wq_bf, xnt, qkv_b, Qd, Kd, Vd);
    attn_mfma<<<dim3(1024), dim3(128), 0, stream>>>(Qd, Kd, Vd, att_t);
    proj_gemm<<<dim3(8, 4, B_), dim3(256), 0, stream>>>(wp_bf, att_t, proj_b, x, out);
}